// Round 4
// baseline (885.397 us; speedup 1.0000x reference)
//
#include <hip/hip_runtime.h>

// ComplexNetAttention on gfx950.
// Pipeline: int8-fakequant -> fused complex QKV GEMM (fp16 MFMA, NT, K=4096;
//   8-phase counted-vmcnt schedule, 256x192 tile) -> cos/sin table +
//   vectorized RoPE -> fused flash attention (barrier-free) -> fakequant -> out GEMM.
//
// R8: flash_attn restructured as BARRIER-FREE independent waves. R3 lesson:
// occupancy 14->32% made it WORSE (207->320us) — the bottleneck is the
// lockstep stage chain (2 barriers + cross-wave LDS softmax merge per
// stage), not wave supply. Now: 4 waves/block, each wave owns 16 Q-rows x
// full D=256; complete row softmax in-wave (no pmax/psum LDS, zero
// __syncthreads); P transposed via per-wave private LDS slice (same-wave
// ds ordering via lgkmcnt); causal mask covers whole jn-tiles. No barriers
// => compiler can pipeline next-stage K loads across PV. setprio on MFMA.

typedef float v4f __attribute__((ext_vector_type(4)));
typedef _Float16 v8h __attribute__((ext_vector_type(8)));
typedef _Float16 v4h __attribute__((ext_vector_type(4)));

typedef const __attribute__((address_space(1))) void glob_void;
typedef __attribute__((address_space(3))) void lds_void;

__device__ __forceinline__ void gload16(const _Float16* gp, _Float16* lp) {
  __builtin_amdgcn_global_load_lds((glob_void*)gp, (lds_void*)lp, 16, 0, 0);
}

// bf16 round-trip (RNE) in fp32 — matches reference's bf16 cos/sin cache.
__device__ __forceinline__ float bf16_rt(float f) {
  union { float f; unsigned u; } a; a.f = f;
  unsigned r = (a.u + 0x7fffu + ((a.u >> 16) & 1u)) & 0xffff0000u;
  union { unsigned u; float f; } b; b.u = r;
  return b.f;
}

#define EPI_QKV 0
#define EPI_OUT 1

#define SBAR()  __builtin_amdgcn_sched_barrier(0)
#define WBAR()  __builtin_amdgcn_s_barrier()
#define LGKM0() asm volatile("s_waitcnt lgkmcnt(0)" ::: "memory")

// ---------------------------------------------------------------------------
// QKV GEMM: C[2048][12288] = A[2048][4096] @ B[12288][4096]^T, fp16, fp32 acc.
// Tile 256x192, BK=64, 512 thr (8 waves 2m x 4n), wave-tile 128x48.
// 8-phase counted-vmcnt schedule (T3+T4), XOR chunk swizzle (0-conflict),
// s_setprio around MFMA clusters (T5), bijective XCD chunking (T1).
// ---------------------------------------------------------------------------
__global__ __launch_bounds__(512, 2) void gemm_qkv256(
    const _Float16* __restrict__ A, const _Float16* __restrict__ B,
    _Float16* __restrict__ Yq, _Float16* __restrict__ vt)
{
  const int p = blockIdx.x;            // 0..511, XCD = p & 7 (round-robin)
  const int xcd = p & 7, s = p >> 3;   // s: 0..63 within chunk
  const int mt = s & 7, ntl = s >> 3;
  const int nt = xcd * 8 + ntl;        // 0..63
  const int m0 = mt << 8;              // *256
  const int n0 = nt * 192;

  __shared__ __align__(16) _Float16 lds[57344];  // 2 bufs x (16384 A + 12288 B)

  const int tid = threadIdx.x, lane = tid & 63, wave = tid >> 6;
  const int quad = lane >> 4, l15 = lane & 15;
  const int wm = wave >> 2, wn = wave & 3;       // 2 x 4 waves

  // staging constants: for gload j covering LDS halfs [j*4096 + tid*8):
  // r = (j&1)*128 + tid>>2, pc = tid&3, lc = pc ^ ((r>>1)&3)
  const int rr = tid >> 2;                                   // 0..127
  const int lc8 = (((tid & 3) ^ ((tid >> 3) & 3)) << 3);     // logical chunk*8
  const _Float16* gA = A + (long long)(m0 + rr) * 4096 + lc8;
  // B tile = 24KB = 3 gloads; gload 1 crosses the ks0/ks1 subtile boundary.
  const _Float16* gBj[3];
#pragma unroll
  for (int j = 0; j < 3; ++j) {
    const int ks = (j == 2) || (j == 1 && tid >= 256);
    const int r = j * 128 + (tid >> 2) - ks * 192;
    gBj[j] = B + (long long)(n0 + r) * 4096 + ks * 32 + lc8;
  }

  // read constants: phys chunk = quad ^ ((l15>>1)&3), constant per lane
  const int co = ((quad ^ ((l15 >> 1) & 3)) << 3);
  const int aBase = (wm * 128 + l15) * 32 + co;
  const int bBase = (wn * 48 + l15) * 32 + co;

  v4f acc[8][3] = {};

  // prologue: stage tile 0 -> buf 0 in canonical order a0,a1,b0,b1,a2,a3,b2
  {
    _Float16* sd = lds + tid * 8;
    gload16(gA, sd);
    gload16(gA + 524288, sd + 4096);          // 128*4096
    gload16(gBj[0], sd + 16384);
    gload16(gBj[1], sd + 20480);
    gload16(gA + 32, sd + 8192);
    gload16(gA + 524288 + 32, sd + 12288);
    gload16(gBj[2], sd + 24576);
  }
  asm volatile("s_waitcnt vmcnt(3)" ::: "memory");  // first-4 of tile 0 done
  WBAR();

  for (int t = 0; t < 64; ++t) {
    const _Float16* As = lds + (t & 1) * 28672;
    const _Float16* Bs = As + 16384;
    _Float16* sd = lds + ((t & 1) ^ 1) * 28672 + tid * 8;
    const int k1 = (t + 1) << 6;
    const bool stg = (t < 63);

    v8h bf[3], af[4];

    // ===== P0: ds bf(ks0)+af(mh0,ks0); stage a0,a1(t+1) =====
    af[0] = *(const v8h*)&As[aBase];
    af[1] = *(const v8h*)&As[aBase + 512];
    af[2] = *(const v8h*)&As[aBase + 1024];
    af[3] = *(const v8h*)&As[aBase + 1536];
    bf[0] = *(const v8h*)&Bs[bBase];
    bf[1] = *(const v8h*)&Bs[bBase + 512];
    bf[2] = *(const v8h*)&Bs[bBase + 1024];
    if (stg) { gload16(gA + k1, sd); gload16(gA + k1 + 524288, sd + 4096); }
    SBAR(); WBAR(); LGKM0(); SBAR();
    __builtin_amdgcn_s_setprio(1);
#pragma unroll
    for (int i = 0; i < 4; ++i)
#pragma unroll
      for (int nf = 0; nf < 3; ++nf)
        acc[i][nf] = __builtin_amdgcn_mfma_f32_16x16x32_f16(af[i], bf[nf], acc[i][nf], 0, 0, 0);
    __builtin_amdgcn_s_setprio(0);
    WBAR();

    // ===== P1: ds af(mh1,ks0); stage b0,b1(t+1); vmcnt(4) =====
    af[0] = *(const v8h*)&As[aBase + 2048];
    af[1] = *(const v8h*)&As[aBase + 2560];
    af[2] = *(const v8h*)&As[aBase + 3072];
    af[3] = *(const v8h*)&As[aBase + 3584];
    if (stg) { gload16(gBj[0] + k1, sd + 16384); gload16(gBj[1] + k1, sd + 20480); }
    SBAR(); WBAR(); LGKM0(); SBAR();
    __builtin_amdgcn_s_setprio(1);
#pragma unroll
    for (int i = 0; i < 4; ++i)
#pragma unroll
      for (int nf = 0; nf < 3; ++nf)
        acc[4 + i][nf] = __builtin_amdgcn_mfma_f32_16x16x32_f16(af[i], bf[nf], acc[4 + i][nf], 0, 0, 0);
    __builtin_amdgcn_s_setprio(0);
    if (stg) asm volatile("s_waitcnt vmcnt(4)" ::: "memory");
    else     asm volatile("s_waitcnt vmcnt(0)" ::: "memory");
    WBAR();

    // ===== P2: ds bf(ks1)+af(mh0,ks1); stage a2,a3(t+1) =====
    bf[0] = *(const v8h*)&Bs[bBase + 6144];
    bf[1] = *(const v8h*)&Bs[bBase + 6656];
    bf[2] = *(const v8h*)&Bs[bBase + 7168];
    af[0] = *(const v8h*)&As[aBase + 8192];
    af[1] = *(const v8h*)&As[aBase + 8704];
    af[2] = *(const v8h*)&As[aBase + 9216];
    af[3] = *(const v8h*)&As[aBase + 9728];
    if (stg) { gload16(gA + k1 + 32, sd + 8192); gload16(gA + k1 + 524288 + 32, sd + 12288); }
    SBAR(); WBAR(); LGKM0(); SBAR();
    __builtin_amdgcn_s_setprio(1);
#pragma unroll
    for (int i = 0; i < 4; ++i)
#pragma unroll
      for (int nf = 0; nf < 3; ++nf)
        acc[i][nf] = __builtin_amdgcn_mfma_f32_16x16x32_f16(af[i], bf[nf], acc[i][nf], 0, 0, 0);
    __builtin_amdgcn_s_setprio(0);
    WBAR();

    // ===== P3: ds af(mh1,ks1); stage b2(t+1); vmcnt(3) =====
    af[0] = *(const v8h*)&As[aBase + 10240];
    af[1] = *(const v8h*)&As[aBase + 10752];
    af[2] = *(const v8h*)&As[aBase + 11264];
    af[3] = *(const v8h*)&As[aBase + 11776];
    if (stg) gload16(gBj[2] + k1, sd + 24576);
    SBAR(); WBAR(); LGKM0(); SBAR();
    __builtin_amdgcn_s_setprio(1);
#pragma unroll
    for (int i = 0; i < 4; ++i)
#pragma unroll
      for (int nf = 0; nf < 3; ++nf)
        acc[4 + i][nf] = __builtin_amdgcn_mfma_f32_16x16x32_f16(af[i], bf[nf], acc[4 + i][nf], 0, 0, 0);
    __builtin_amdgcn_s_setprio(0);
    if (stg) asm volatile("s_waitcnt vmcnt(3)" ::: "memory");
    WBAR();
  }

  // epilogue: C/D layout col=lane&15, row=quad*4+reg (m89/m91-verified)
#pragma unroll
  for (int mf = 0; mf < 8; ++mf) {
#pragma unroll
    for (int nf = 0; nf < 3; ++nf) {
      const int col = n0 + wn * 48 + nf * 16 + l15;
      const int row0 = m0 + wm * 128 + mf * 16 + quad * 4;   // multiple of 4
      if (col >= 8192) {
        // v projection -> vt[NH][256][2048], packed 4 rows per store
        const int c = col - 8192;
        const int hh = (c & 2047) >> 7;
        const int dcol = (c < 2048) ? (c & 127) : (128 + (c & 127));
        v4h pk;
#pragma unroll
        for (int r = 0; r < 4; ++r) pk[r] = (_Float16)acc[mf][nf][r];
        *(v4h*)(vt + ((long long)(hh * 256 + dcol)) * 2048 + row0) = pk;
      } else {
#pragma unroll
        for (int r = 0; r < 4; ++r)
          Yq[(long long)(row0 + r) * 8192 + col] = (_Float16)acc[mf][nf][r];
      }
    }
  }
}

// ---------------------------------------------------------------------------
// old NT GEMM template (kept for the output projection): 128x128, BK=32,
// 256 thr, XOR-swizzled LDS, global_load_lds staging.
// ---------------------------------------------------------------------------
template<int EPI>
__global__ __launch_bounds__(256) void gemm_nt(
    const _Float16* __restrict__ A, const _Float16* __restrict__ B,
    void* __restrict__ Cv, int K, int lda, int ldb, int ldc,
    _Float16* __restrict__ vtout)
{
  const int m0 = blockIdx.x * 128, n0 = blockIdx.y * 128;

  __shared__ __align__(16) _Float16 As[128 * 32];
  __shared__ __align__(16) _Float16 Bs[128 * 32];

  const int tid = threadIdx.x, lane = tid & 63, wave = tid >> 6;
  const int off0 = tid * 8, off1 = 2048 + tid * 8;
  const int r0 = off0 >> 5, r1 = off1 >> 5;
  const int c0 = ((((off0 >> 3) & 3) ^ ((r0 >> 1) & 3)) << 3);
  const int c1 = ((((off1 >> 3) & 3) ^ ((r1 >> 1) & 3)) << 3);
  const _Float16* ga0 = A + (long long)(m0 + r0) * lda + c0;
  const _Float16* ga1 = A + (long long)(m0 + r1) * lda + c1;
  const _Float16* gb0 = B + (long long)(n0 + r0) * ldb + c0;
  const _Float16* gb1 = B + (long long)(n0 + r1) * ldb + c1;

  const int mr = (wave >> 1) * 64 + (lane & 15);
  const int nr = (wave & 1) * 64 + (lane & 15);
  const int kq = lane >> 4;

  v4f acc[4][4] = {};

  for (int k0 = 0; k0 < K; k0 += 32) {
    gload16(ga0 + k0, As + off0);
    gload16(ga1 + k0, As + off1);
    gload16(gb0 + k0, Bs + off0);
    gload16(gb1 + k0, Bs + off1);
    __syncthreads();
    v8h a[4], b[4];
#pragma unroll
    for (int i = 0; i < 4; ++i) {
      const int r = mr + i * 16;
      a[i] = *(const v8h*)&As[r * 32 + ((kq ^ ((r >> 1) & 3)) << 3)];
    }
#pragma unroll
    for (int j = 0; j < 4; ++j) {
      const int r = nr + j * 16;
      b[j] = *(const v8h*)&Bs[r * 32 + ((kq ^ ((r >> 1) & 3)) << 3)];
    }
#pragma unroll
    for (int i = 0; i < 4; ++i)
#pragma unroll
      for (int j = 0; j < 4; ++j)
        acc[i][j] = __builtin_amdgcn_mfma_f32_16x16x32_f16(a[i], b[j], acc[i][j], 0, 0, 0);
    __syncthreads();
  }

  const int cr = (wave >> 1) * 64 + (lane >> 4) * 4;
  const int cc = (wave & 1) * 64 + (lane & 15);
#pragma unroll
  for (int i = 0; i < 4; ++i)
#pragma unroll
    for (int j = 0; j < 4; ++j) {
      const int col = n0 + cc + j * 16;
      if (EPI == EPI_QKV && col >= 8192) {
        const int c = col - 8192;
        const int hh = (c & 2047) >> 7;
        const int dcol = (c < 2048) ? (c & 127) : (128 + (c & 127));
        const int row0 = m0 + cr + i * 16;
        v4h pk;
#pragma unroll
        for (int r = 0; r < 4; ++r) pk[r] = (_Float16)acc[i][j][r];
        *(v4h*)(vtout + ((long long)(hh * 256 + dcol)) * 2048 + row0) = pk;
      } else {
#pragma unroll
        for (int r = 0; r < 4; ++r) {
          const int row = m0 + cr + i * 16 + r;
          const float v = acc[i][j][r];
          if (EPI == EPI_QKV) {
            ((_Float16*)Cv)[(long long)row * ldc + col] = (_Float16)v;
          } else { // EPI_OUT
            float* O = (float*)Cv;
            if (col < 2048) O[(long long)row * 2048 + col] = v;
            else O[2048ll * 2048 + (long long)row * 2048 + (col - 2048)] = v;
          }
        }
      }
    }
}

// per-row int8 fake-quant of two [2048][2048] fp32 sources -> fp16 [2048][4096]
__global__ __launch_bounds__(256) void quant_rows(
    const float* __restrict__ s0, const float* __restrict__ s1,
    _Float16* __restrict__ dst)
{
  const int t = blockIdx.x, y = blockIdx.y;
  const float* src = (y ? s1 : s0) + (long long)t * 2048;
  const int tid = threadIdx.x, lane = tid & 63, wave = tid >> 6;
  __shared__ float rbuf[4];
  const v4f a = *(const v4f*)(src + tid * 4);
  const v4f b = *(const v4f*)(src + 1024 + tid * 4);
  float m = 0.f;
#pragma unroll
  for (int k = 0; k < 4; ++k)
    m = fmaxf(m, fmaxf(fabsf(a[k]), fabsf(b[k])));
  for (int o = 1; o < 64; o <<= 1) m = fmaxf(m, __shfl_xor(m, o, 64));
  if (lane == 0) rbuf[wave] = m;
  __syncthreads();
  m = fmaxf(fmaxf(rbuf[0], rbuf[1]), fmaxf(rbuf[2], rbuf[3]));
  const float scale = 127.f / fmaxf(m, 1e-5f);
  const float inv = 1.f / scale;
  _Float16* d = dst + (long long)t * 4096 + (long long)y * 2048 + tid * 4;
  v4h qa, qb;
#pragma unroll
  for (int k = 0; k < 4; ++k) {
    qa[k] = (_Float16)(fminf(fmaxf(rintf(a[k] * scale), -128.f), 127.f) * inv);
    qb[k] = (_Float16)(fminf(fmaxf(rintf(b[k] * scale), -128.f), 127.f) * inv);
  }
  *(v4h*)d = qa;
  *(v4h*)(d + 1024) = qb;
}

// Build concatenated complex weight matrices (fp16)
__global__ __launch_bounds__(256) void wprep(
    const float* __restrict__ Wq_r, const float* __restrict__ Wq_i,
    const float* __restrict__ Wk_r, const float* __restrict__ Wk_i,
    const float* __restrict__ Wv_r, const float* __restrict__ Wv_i,
    const float* __restrict__ Wo_r, const float* __restrict__ Wo_i,
    _Float16* __restrict__ Bqkv, _Float16* __restrict__ Bo)
{
  const float* Ws[8] = {Wq_r, Wq_i, Wk_r, Wk_i, Wv_r, Wv_i, Wo_r, Wo_i};
  const int i = blockIdx.x * 256 + threadIdx.x;
  const int w = i >> 18;
  const int rem = i & 262143;
  const int j = rem >> 7;
  const int cb = (rem & 127) * 16;
  const float* src = Ws[w] + (long long)j * 2048 + cb;
  _Float16* Bp = (w < 6) ? (Bqkv + (long long)(w >> 1) * 4096 * 4096) : Bo;
  const int isI = w & 1;
  _Float16* d1 = Bp + (long long)j * 4096 + (isI ? 2048 + cb : cb);
  _Float16* d2 = Bp + (long long)(2048 + j) * 4096 + (isI ? cb : 2048 + cb);
  const float sg2 = isI ? 1.f : -1.f;
#pragma unroll
  for (int q = 0; q < 4; ++q) {
    const v4f v = *(const v4f*)(src + q * 4);
    v4h o1, o2;
#pragma unroll
    for (int k = 0; k < 4; ++k) {
      o1[k] = (_Float16)v[k];
      o2[k] = (_Float16)(v[k] * sg2);
    }
    *(v4h*)(d1 + q * 4) = o1;
    *(v4h*)(d2 + q * 4) = o2;
  }
}

// cos/sin table [T][128] float2, bf16-rounded
__global__ __launch_bounds__(256) void trig_kernel(
    const int* __restrict__ pos, float* __restrict__ cs)
{
  const int t = blockIdx.x * 2 + (threadIdx.x >> 7);
  const int d = threadIdx.x & 127;
  const float invf = (float)pow(10000.0, -(double)d / 128.0);
  const float fr = (float)pos[t] * invf;
  const double fd = (double)fr;
  cs[((long long)t * 128 + d) * 2]     = bf16_rt((float)cos(fd));
  cs[((long long)t * 128 + d) * 2 + 1] = bf16_rt((float)sin(fd));
}

// vectorized RoPE: Yq [T][8192] (qr|qi|kr|ki) -> qc/kc [NH][T][256] fp16
__global__ __launch_bounds__(256) void rope_kernel(
    const _Float16* __restrict__ Yq, const float* __restrict__ cs,
    _Float16* __restrict__ qc, _Float16* __restrict__ kc)
{
  const int idx = blockIdx.x * 256 + threadIdx.x;
  const int d0 = (idx & 15) * 8;
  const int h  = (idx >> 4) & 15;
  const int t  = idx >> 8;
  const _Float16* y = Yq + (long long)t * 8192 + h * 128 + d0;
  const v8h qr8 = *(const v8h*)(y);
  const v8h qi8 = *(const v8h*)(y + 2048);
  const v8h kr8 = *(const v8h*)(y + 4096);
  const v8h ki8 = *(const v8h*)(y + 6144);
  const float* cp = cs + ((long long)t * 128 + d0) * 2;
  v8h qro, qio, kro, kio;
#pragma unroll
  for (int u = 0; u < 8; ++u) {
    const float c = cp[u * 2], s = cp[u * 2 + 1];
    const float qr = (float)qr8[u], qi = (float)qi8[u];
    const float kr = (float)kr8[u], ki = (float)ki8[u];
    qro[u] = (_Float16)(qr * c - qi * s);
    qio[u] = (_Float16)(qi * c + qr * s);
    kro[u] = (_Float16)(kr * c - ki * s);
    kio[u] = (_Float16)(ki * c + kr * s);
  }
  _Float16* qo = qc + ((long long)h * 2048 + t) * 256 + d0;
  _Float16* ko = kc + ((long long)h * 2048 + t) * 256 + d0;
  *(v8h*)qo = qro; *(v8h*)(qo + 128) = qio;
  *(v8h*)ko = kro; *(v8h*)(ko + 128) = kio;
}

// Fused causal flash attention, BARRIER-FREE independent waves (R8).
// Block = 4 waves x 16 Q-rows = 64 rows of one head; grid 32x16.
// Each wave: full row softmax in-register (jn-sum + 16-lane shfl), full
// D=256 output (acc_o[16]); P transposed through per-wave LDS slice.
// K/V direct from global (L2-hot). Zero __syncthreads.
__global__ __launch_bounds__(256, 2) void flash_attn(
    const _Float16* __restrict__ qc, const _Float16* __restrict__ kc,
    const _Float16* __restrict__ vt, float* __restrict__ attn)
{
  __shared__ __align__(16) _Float16 Ps[4][16][72];   // per-wave slices

  const int h  = blockIdx.y;
  // load-balance remap: pair small-qt with large-qt across heads
  const int qt = ((h >> 3) & 1) ? (31 - (int)blockIdx.x) : (int)blockIdx.x;
  const int q0 = qt * 64;
  const int tid = threadIdx.x, lane = tid & 63, wave = tid >> 6;
  const int quad = lane >> 4, l15 = lane & 15;

  const _Float16* qh = qc + (long long)h * 2048 * 256;
  const _Float16* kh = kc + (long long)h * 2048 * 256;
  const _Float16* vh = vt + (long long)h * 256 * 2048;

  const int wrow = q0 + wave * 16;     // this wave's first Q row

  // Q fragments in registers, pre-scaled by log2(e)/16 (exp2-domain softmax)
  const _Float16 scl = (_Float16)0.09016844f;
  v8h qf[8];
  {
    const int t = wrow + l15;
#pragma unroll
    for (int ks = 0; ks < 8; ++ks) {
      v8h q = *(const v8h*)(qh + (long long)t * 256 + ks * 32 + quad * 8);
#pragma unroll
      for (int u = 0; u < 8; ++u) q[u] *= scl;
      qf[ks] = q;
    }
  }

  float mrow[4], lrow[4];
  v4f acc_o[16];
#pragma unroll
  for (int r = 0; r < 4; ++r) { mrow[r] = -1e30f; lrow[r] = 0.f; }
#pragma unroll
  for (int nt = 0; nt < 16; ++nt) acc_o[nt] = (v4f){0.f, 0.f, 0.f, 0.f};

  for (int st = 0; st <= qt; ++st) {
    const int s0 = st * 64;
    const bool diag = (st == qt);

    // S rows = Q[wave rows] @ K[s0..s0+63]^T  (16x64), K direct from L2
    v4f sa[4] = {};
#pragma unroll
    for (int ks = 0; ks < 8; ++ks) {
      v8h bk[4];
#pragma unroll
      for (int jn = 0; jn < 4; ++jn)
        bk[jn] = *(const v8h*)(kh + (long long)(s0 + jn * 16 + l15) * 256
                               + ks * 32 + quad * 8);
      __builtin_amdgcn_s_setprio(1);
#pragma unroll
      for (int jn = 0; jn < 4; ++jn)
        sa[jn] = __builtin_amdgcn_mfma_f32_16x16x32_f16(qf[ks], bk[jn], sa[jn], 0, 0, 0);
      __builtin_amdgcn_s_setprio(0);
    }

    // causal mask (diag stage: mask cl>rl; jn-tiles above wave fully masked)
    float pm[4];
#pragma unroll
    for (int r = 0; r < 4; ++r) pm[r] = -1e30f;
#pragma unroll
    for (int jn = 0; jn < 4; ++jn)
#pragma unroll
      for (int r = 0; r < 4; ++r) {
        float v = sa[jn][r];          // already log2-scaled
        if (diag) {
          const int rl = wrow + quad * 4 + r;
          const int cl = s0 + jn * 16 + l15;
          if (cl > rl) v = -1e30f;
        }
        sa[jn][r] = v;
        pm[r] = fmaxf(pm[r], v);
      }
    // full row max within wave: reduce across the 16 col-lanes
#pragma unroll
    for (int o = 1; o < 16; o <<= 1)
#pragma unroll
      for (int r = 0; r < 4; ++r)
        pm[r] = fmaxf(pm[r], __shfl_xor(pm[r], o, 64));

    float al[4], ps[4];
#pragma unroll
    for (int r = 0; r < 4; ++r) {
      const float mn = fmaxf(mrow[r], pm[r]);
      al[r] = __builtin_amdgcn_exp2f(mrow[r] - mn);
      mrow[r] = mn;
      ps[r] = 0.f;
    }
#pragma unroll
    for (int jn = 0; jn < 4; ++jn)
#pragma unroll
      for (int r = 0; r < 4; ++r) {
        const float e = __builtin_amdgcn_exp2f(sa[jn][r] - mrow[r]);
        ps[r] += e;
        Ps[wave][quad * 4 + r][jn * 16 + l15] = (_Float16)e;
      }
#pragma unroll
    for (int o = 1; o < 16; o <<= 1)
#pragma unroll
      for (int r = 0; r < 4; ++r)
        ps[r] += __shfl_xor(ps[r], o, 64);
#pragma unroll
    for (int r = 0; r < 4; ++r)
      lrow[r] = lrow[r] * al[r] + ps[r];
#pragma unroll
    for (int nt = 0; nt < 16; ++nt)
#pragma unroll
      for (int r = 0; r < 4; ++r)
        acc_o[nt][r] *= al[r];

    // O += P @ V ; P via per-wave LDS transpose (same-wave lgkmcnt ordering),
    // V direct from global (L2-hot)
#pragma unroll
    for (int kc2 = 0; kc2 < 2; ++kc2) {
      const v8h pa = *(const v8h*)&Ps[wave][l15][kc2 * 32 + quad * 8];
      __builtin_amdgcn_s_setprio(1);
#pragma unroll
      for (int nt = 0; nt < 16; ++nt) {
        const v8h vb = *(const v8h*)(vh + (long long)(nt * 16 + l15) * 2048
                                     + s0 + kc2 * 32 + quad * 8);
        acc_o[nt] = __builtin_amdgcn_mfma_f32_16x16x32_f16(pa, vb, acc_o[nt], 0, 0, 0);
      }
      __builtin_amdgcn_s_setprio(0);
    }
  }

  // epilogue: O/l -> attn (r-part at 0, i-part at +2048*2048 floats)
  float inv[4];
#pragma unroll
  for (int r = 0; r < 4; ++r) inv[r] = 1.f / lrow[r];
#pragma unroll
  for (int nt = 0; nt < 16; ++nt) {
    const int d = nt * 16 + l15;
    float* dst = attn + ((d < 128) ? 0ll : (2048ll * 2048)) + (h * 128 + (d & 127));
#pragma unroll
    for (int r = 0; r < 4; ++r) {
      const int t = wrow + quad * 4 + r;
      dst[(long long)t * 2048] = acc_o[nt][r] * inv[r];
    }
  }
}

extern "C" void kernel_launch(void* const* d_in, const int* in_sizes, int n_in,
                              void* d_out, int out_size, void* d_ws, size_t ws_size,
                              hipStream_t stream) {
  const float* hr   = (const float*)d_in[0];
  const float* hi   = (const float*)d_in[1];
  const int*   pos  = (const int*)d_in[2];
  const float* Wq_r = (const float*)d_in[3];
  const float* Wq_i = (const float*)d_in[4];
  const float* Wk_r = (const float*)d_in[5];
  const float* Wk_i = (const float*)d_in[6];
  const float* Wv_r = (const float*)d_in[7];
  const float* Wv_i = (const float*)d_in[8];
  const float* Wo_r = (const float*)d_in[9];
  const float* Wo_i = (const float*)d_in[10];

  char* ws = (char*)d_ws;
  _Float16* Bqkv = (_Float16*)(ws);                    // 96MB
  float*    attn = (float*)   (ws);                    // 32MB (alias, post-QKV)
  float*    cs   = (float*)   (ws + (32ll  << 20));    // 2MB  (alias, post-QKV)
  _Float16* Bo   = (_Float16*)(ws + (96ll  << 20));    // 32MB
  _Float16* Ac   = (_Float16*)(ws + (128ll << 20));    // 16MB
  _Float16* Yq   = (_Float16*)(ws + (144ll << 20));    // 32MB (q,k only)
  _Float16* qc   = (_Float16*)(ws + (176ll << 20));    // 16MB
  _Float16* kc   = (_Float16*)(ws + (192ll << 20));    // 16MB
  _Float16* vt   = (_Float16*)(ws + (208ll << 20));    // 16MB

  quant_rows<<<dim3(2048, 2), 256, 0, stream>>>(hr, hi, Ac);
  wprep<<<8192, 256, 0, stream>>>(Wq_r, Wq_i, Wk_r, Wk_i, Wv_r, Wv_i, Wo_r, Wo_i, Bqkv, Bo);
  // fused QKV: [qr|qi](2048x4096) @ Bqkv(12288x4096)^T -> Yq (q,k) + vt (v)
  gemm_qkv256<<<512, 512, 0, stream>>>(Ac, Bqkv, Yq, vt);
  trig_kernel<<<1024, 256, 0, stream>>>(pos, cs);
  rope_kernel<<<2048, 256, 0, stream>>>(Yq, cs, qc, kc);
  flash_attn<<<dim3(32, 16), 256, 0, stream>>>(qc, kc, vt, attn);
  quant_rows<<<dim3(2048, 2), 256, 0, stream>>>(attn, attn + 2048ll * 2048, Ac);
  gemm_nt<EPI_OUT><<<dim3(16, 32), 256, 0, stream>>>(
      Ac, Bo, d_out, 4096, 4096, 4096, 0, nullptr);
}

// Round 5
// 774.102 us; speedup vs baseline: 1.1438x; 1.1438x over previous
//
#include <hip/hip_runtime.h>

// ComplexNetAttention on gfx950.
// Pipeline: int8-fakequant -> fused complex QKV GEMM (fp16 MFMA, NT, K=4096;
//   8-phase counted-vmcnt schedule, 256x192 tile) -> cos/sin table +
//   vectorized RoPE -> fused flash attention v2 -> fakequant -> out GEMM.
//
// R9: flash_attn = R2's verified 4-wave cooperative structure (best measured:
// 207us) with ONE change: the two per-stage __syncthreads are replaced by
// {sched_barrier; lgkmcnt(0); s_barrier; sched_barrier} — raw HW barrier
// with LDS drain only, NO vmcnt(0) drain (T4 applied to attention).
// R3/R4 lessons: occupancy boost made it worse (lockstep chain), barrier-free
// waves made it worse (4x K/V duplication). The chain's removable cost is
// the compiler's vmcnt(0) drain at each __syncthreads, which kills
// cross-stage K/V load pipelining. Plus T5 setprio on MFMA clusters (m191).

typedef float v4f __attribute__((ext_vector_type(4)));
typedef _Float16 v8h __attribute__((ext_vector_type(8)));
typedef _Float16 v4h __attribute__((ext_vector_type(4)));

typedef const __attribute__((address_space(1))) void glob_void;
typedef __attribute__((address_space(3))) void lds_void;

__device__ __forceinline__ void gload16(const _Float16* gp, _Float16* lp) {
  __builtin_amdgcn_global_load_lds((glob_void*)gp, (lds_void*)lp, 16, 0, 0);
}

// bf16 round-trip (RNE) in fp32 — matches reference's bf16 cos/sin cache.
__device__ __forceinline__ float bf16_rt(float f) {
  union { float f; unsigned u; } a; a.f = f;
  unsigned r = (a.u + 0x7fffu + ((a.u >> 16) & 1u)) & 0xffff0000u;
  union { unsigned u; float f; } b; b.u = r;
  return b.f;
}

#define EPI_QKV 0
#define EPI_OUT 1

#define SBAR()  __builtin_amdgcn_sched_barrier(0)
#define WBAR()  __builtin_amdgcn_s_barrier()
#define LGKM0() asm volatile("s_waitcnt lgkmcnt(0)" ::: "memory")
// LDS-only barrier: drains LDS ops, leaves global loads in flight.
#define LDS_BARRIER() do { SBAR(); LGKM0(); WBAR(); SBAR(); } while (0)

// ---------------------------------------------------------------------------
// QKV GEMM: C[2048][12288] = A[2048][4096] @ B[12288][4096]^T, fp16, fp32 acc.
// Tile 256x192, BK=64, 512 thr (8 waves 2m x 4n), wave-tile 128x48.
// 8-phase counted-vmcnt schedule (T3+T4), XOR chunk swizzle (0-conflict),
// s_setprio around MFMA clusters (T5), bijective XCD chunking (T1).
// ---------------------------------------------------------------------------
__global__ __launch_bounds__(512, 2) void gemm_qkv256(
    const _Float16* __restrict__ A, const _Float16* __restrict__ B,
    _Float16* __restrict__ Yq, _Float16* __restrict__ vt)
{
  const int p = blockIdx.x;            // 0..511, XCD = p & 7 (round-robin)
  const int xcd = p & 7, s = p >> 3;   // s: 0..63 within chunk
  const int mt = s & 7, ntl = s >> 3;
  const int nt = xcd * 8 + ntl;        // 0..63
  const int m0 = mt << 8;              // *256
  const int n0 = nt * 192;

  __shared__ __align__(16) _Float16 lds[57344];  // 2 bufs x (16384 A + 12288 B)

  const int tid = threadIdx.x, lane = tid & 63, wave = tid >> 6;
  const int quad = lane >> 4, l15 = lane & 15;
  const int wm = wave >> 2, wn = wave & 3;       // 2 x 4 waves

  // staging constants: for gload j covering LDS halfs [j*4096 + tid*8):
  // r = (j&1)*128 + tid>>2, pc = tid&3, lc = pc ^ ((r>>1)&3)
  const int rr = tid >> 2;                                   // 0..127
  const int lc8 = (((tid & 3) ^ ((tid >> 3) & 3)) << 3);     // logical chunk*8
  const _Float16* gA = A + (long long)(m0 + rr) * 4096 + lc8;
  // B tile = 24KB = 3 gloads; gload 1 crosses the ks0/ks1 subtile boundary.
  const _Float16* gBj[3];
#pragma unroll
  for (int j = 0; j < 3; ++j) {
    const int ks = (j == 2) || (j == 1 && tid >= 256);
    const int r = j * 128 + (tid >> 2) - ks * 192;
    gBj[j] = B + (long long)(n0 + r) * 4096 + ks * 32 + lc8;
  }

  // read constants: phys chunk = quad ^ ((l15>>1)&3), constant per lane
  const int co = ((quad ^ ((l15 >> 1) & 3)) << 3);
  const int aBase = (wm * 128 + l15) * 32 + co;
  const int bBase = (wn * 48 + l15) * 32 + co;

  v4f acc[8][3] = {};

  // prologue: stage tile 0 -> buf 0 in canonical order a0,a1,b0,b1,a2,a3,b2
  {
    _Float16* sd = lds + tid * 8;
    gload16(gA, sd);
    gload16(gA + 524288, sd + 4096);          // 128*4096
    gload16(gBj[0], sd + 16384);
    gload16(gBj[1], sd + 20480);
    gload16(gA + 32, sd + 8192);
    gload16(gA + 524288 + 32, sd + 12288);
    gload16(gBj[2], sd + 24576);
  }
  asm volatile("s_waitcnt vmcnt(3)" ::: "memory");  // first-4 of tile 0 done
  WBAR();

  for (int t = 0; t < 64; ++t) {
    const _Float16* As = lds + (t & 1) * 28672;
    const _Float16* Bs = As + 16384;
    _Float16* sd = lds + ((t & 1) ^ 1) * 28672 + tid * 8;
    const int k1 = (t + 1) << 6;
    const bool stg = (t < 63);

    v8h bf[3], af[4];

    // ===== P0: ds bf(ks0)+af(mh0,ks0); stage a0,a1(t+1) =====
    af[0] = *(const v8h*)&As[aBase];
    af[1] = *(const v8h*)&As[aBase + 512];
    af[2] = *(const v8h*)&As[aBase + 1024];
    af[3] = *(const v8h*)&As[aBase + 1536];
    bf[0] = *(const v8h*)&Bs[bBase];
    bf[1] = *(const v8h*)&Bs[bBase + 512];
    bf[2] = *(const v8h*)&Bs[bBase + 1024];
    if (stg) { gload16(gA + k1, sd); gload16(gA + k1 + 524288, sd + 4096); }
    SBAR(); WBAR(); LGKM0(); SBAR();
    __builtin_amdgcn_s_setprio(1);
#pragma unroll
    for (int i = 0; i < 4; ++i)
#pragma unroll
      for (int nf = 0; nf < 3; ++nf)
        acc[i][nf] = __builtin_amdgcn_mfma_f32_16x16x32_f16(af[i], bf[nf], acc[i][nf], 0, 0, 0);
    __builtin_amdgcn_s_setprio(0);
    WBAR();

    // ===== P1: ds af(mh1,ks0); stage b0,b1(t+1); vmcnt(4) =====
    af[0] = *(const v8h*)&As[aBase + 2048];
    af[1] = *(const v8h*)&As[aBase + 2560];
    af[2] = *(const v8h*)&As[aBase + 3072];
    af[3] = *(const v8h*)&As[aBase + 3584];
    if (stg) { gload16(gBj[0] + k1, sd + 16384); gload16(gBj[1] + k1, sd + 20480); }
    SBAR(); WBAR(); LGKM0(); SBAR();
    __builtin_amdgcn_s_setprio(1);
#pragma unroll
    for (int i = 0; i < 4; ++i)
#pragma unroll
      for (int nf = 0; nf < 3; ++nf)
        acc[4 + i][nf] = __builtin_amdgcn_mfma_f32_16x16x32_f16(af[i], bf[nf], acc[4 + i][nf], 0, 0, 0);
    __builtin_amdgcn_s_setprio(0);
    if (stg) asm volatile("s_waitcnt vmcnt(4)" ::: "memory");
    else     asm volatile("s_waitcnt vmcnt(0)" ::: "memory");
    WBAR();

    // ===== P2: ds bf(ks1)+af(mh0,ks1); stage a2,a3(t+1) =====
    bf[0] = *(const v8h*)&Bs[bBase + 6144];
    bf[1] = *(const v8h*)&Bs[bBase + 6656];
    bf[2] = *(const v8h*)&Bs[bBase + 7168];
    af[0] = *(const v8h*)&As[aBase + 8192];
    af[1] = *(const v8h*)&As[aBase + 8704];
    af[2] = *(const v8h*)&As[aBase + 9216];
    af[3] = *(const v8h*)&As[aBase + 9728];
    if (stg) { gload16(gA + k1 + 32, sd + 8192); gload16(gA + k1 + 524288 + 32, sd + 12288); }
    SBAR(); WBAR(); LGKM0(); SBAR();
    __builtin_amdgcn_s_setprio(1);
#pragma unroll
    for (int i = 0; i < 4; ++i)
#pragma unroll
      for (int nf = 0; nf < 3; ++nf)
        acc[i][nf] = __builtin_amdgcn_mfma_f32_16x16x32_f16(af[i], bf[nf], acc[i][nf], 0, 0, 0);
    __builtin_amdgcn_s_setprio(0);
    WBAR();

    // ===== P3: ds af(mh1,ks1); stage b2(t+1); vmcnt(3) =====
    af[0] = *(const v8h*)&As[aBase + 10240];
    af[1] = *(const v8h*)&As[aBase + 10752];
    af[2] = *(const v8h*)&As[aBase + 11264];
    af[3] = *(const v8h*)&As[aBase + 11776];
    if (stg) gload16(gBj[2] + k1, sd + 24576);
    SBAR(); WBAR(); LGKM0(); SBAR();
    __builtin_amdgcn_s_setprio(1);
#pragma unroll
    for (int i = 0; i < 4; ++i)
#pragma unroll
      for (int nf = 0; nf < 3; ++nf)
        acc[4 + i][nf] = __builtin_amdgcn_mfma_f32_16x16x32_f16(af[i], bf[nf], acc[4 + i][nf], 0, 0, 0);
    __builtin_amdgcn_s_setprio(0);
    if (stg) asm volatile("s_waitcnt vmcnt(3)" ::: "memory");
    WBAR();
  }

  // epilogue: C/D layout col=lane&15, row=quad*4+reg (m89/m91-verified)
#pragma unroll
  for (int mf = 0; mf < 8; ++mf) {
#pragma unroll
    for (int nf = 0; nf < 3; ++nf) {
      const int col = n0 + wn * 48 + nf * 16 + l15;
      const int row0 = m0 + wm * 128 + mf * 16 + quad * 4;   // multiple of 4
      if (col >= 8192) {
        // v projection -> vt[NH][256][2048], packed 4 rows per store
        const int c = col - 8192;
        const int hh = (c & 2047) >> 7;
        const int dcol = (c < 2048) ? (c & 127) : (128 + (c & 127));
        v4h pk;
#pragma unroll
        for (int r = 0; r < 4; ++r) pk[r] = (_Float16)acc[mf][nf][r];
        *(v4h*)(vt + ((long long)(hh * 256 + dcol)) * 2048 + row0) = pk;
      } else {
#pragma unroll
        for (int r = 0; r < 4; ++r)
          Yq[(long long)(row0 + r) * 8192 + col] = (_Float16)acc[mf][nf][r];
      }
    }
  }
}

// ---------------------------------------------------------------------------
// old NT GEMM template (kept for the output projection): 128x128, BK=32,
// 256 thr, XOR-swizzled LDS, global_load_lds staging.
// ---------------------------------------------------------------------------
template<int EPI>
__global__ __launch_bounds__(256) void gemm_nt(
    const _Float16* __restrict__ A, const _Float16* __restrict__ B,
    void* __restrict__ Cv, int K, int lda, int ldb, int ldc,
    _Float16* __restrict__ vtout)
{
  const int m0 = blockIdx.x * 128, n0 = blockIdx.y * 128;

  __shared__ __align__(16) _Float16 As[128 * 32];
  __shared__ __align__(16) _Float16 Bs[128 * 32];

  const int tid = threadIdx.x, lane = tid & 63, wave = tid >> 6;
  const int off0 = tid * 8, off1 = 2048 + tid * 8;
  const int r0 = off0 >> 5, r1 = off1 >> 5;
  const int c0 = ((((off0 >> 3) & 3) ^ ((r0 >> 1) & 3)) << 3);
  const int c1 = ((((off1 >> 3) & 3) ^ ((r1 >> 1) & 3)) << 3);
  const _Float16* ga0 = A + (long long)(m0 + r0) * lda + c0;
  const _Float16* ga1 = A + (long long)(m0 + r1) * lda + c1;
  const _Float16* gb0 = B + (long long)(n0 + r0) * ldb + c0;
  const _Float16* gb1 = B + (long long)(n0 + r1) * ldb + c1;

  const int mr = (wave >> 1) * 64 + (lane & 15);
  const int nr = (wave & 1) * 64 + (lane & 15);
  const int kq = lane >> 4;

  v4f acc[4][4] = {};

  for (int k0 = 0; k0 < K; k0 += 32) {
    gload16(ga0 + k0, As + off0);
    gload16(ga1 + k0, As + off1);
    gload16(gb0 + k0, Bs + off0);
    gload16(gb1 + k0, Bs + off1);
    __syncthreads();
    v8h a[4], b[4];
#pragma unroll
    for (int i = 0; i < 4; ++i) {
      const int r = mr + i * 16;
      a[i] = *(const v8h*)&As[r * 32 + ((kq ^ ((r >> 1) & 3)) << 3)];
    }
#pragma unroll
    for (int j = 0; j < 4; ++j) {
      const int r = nr + j * 16;
      b[j] = *(const v8h*)&Bs[r * 32 + ((kq ^ ((r >> 1) & 3)) << 3)];
    }
#pragma unroll
    for (int i = 0; i < 4; ++i)
#pragma unroll
      for (int j = 0; j < 4; ++j)
        acc[i][j] = __builtin_amdgcn_mfma_f32_16x16x32_f16(a[i], b[j], acc[i][j], 0, 0, 0);
    __syncthreads();
  }

  const int cr = (wave >> 1) * 64 + (lane >> 4) * 4;
  const int cc = (wave & 1) * 64 + (lane & 15);
#pragma unroll
  for (int i = 0; i < 4; ++i)
#pragma unroll
    for (int j = 0; j < 4; ++j) {
      const int col = n0 + cc + j * 16;
      if (EPI == EPI_QKV && col >= 8192) {
        const int c = col - 8192;
        const int hh = (c & 2047) >> 7;
        const int dcol = (c < 2048) ? (c & 127) : (128 + (c & 127));
        const int row0 = m0 + cr + i * 16;
        v4h pk;
#pragma unroll
        for (int r = 0; r < 4; ++r) pk[r] = (_Float16)acc[i][j][r];
        *(v4h*)(vtout + ((long long)(hh * 256 + dcol)) * 2048 + row0) = pk;
      } else {
#pragma unroll
        for (int r = 0; r < 4; ++r) {
          const int row = m0 + cr + i * 16 + r;
          const float v = acc[i][j][r];
          if (EPI == EPI_QKV) {
            ((_Float16*)Cv)[(long long)row * ldc + col] = (_Float16)v;
          } else { // EPI_OUT
            float* O = (float*)Cv;
            if (col < 2048) O[(long long)row * 2048 + col] = v;
            else O[2048ll * 2048 + (long long)row * 2048 + (col - 2048)] = v;
          }
        }
      }
    }
}

// per-row int8 fake-quant of two [2048][2048] fp32 sources -> fp16 [2048][4096]
__global__ __launch_bounds__(256) void quant_rows(
    const float* __restrict__ s0, const float* __restrict__ s1,
    _Float16* __restrict__ dst)
{
  const int t = blockIdx.x, y = blockIdx.y;
  const float* src = (y ? s1 : s0) + (long long)t * 2048;
  const int tid = threadIdx.x, lane = tid & 63, wave = tid >> 6;
  __shared__ float rbuf[4];
  const v4f a = *(const v4f*)(src + tid * 4);
  const v4f b = *(const v4f*)(src + 1024 + tid * 4);
  float m = 0.f;
#pragma unroll
  for (int k = 0; k < 4; ++k)
    m = fmaxf(m, fmaxf(fabsf(a[k]), fabsf(b[k])));
  for (int o = 1; o < 64; o <<= 1) m = fmaxf(m, __shfl_xor(m, o, 64));
  if (lane == 0) rbuf[wave] = m;
  __syncthreads();
  m = fmaxf(fmaxf(rbuf[0], rbuf[1]), fmaxf(rbuf[2], rbuf[3]));
  const float scale = 127.f / fmaxf(m, 1e-5f);
  const float inv = 1.f / scale;
  _Float16* d = dst + (long long)t * 4096 + (long long)y * 2048 + tid * 4;
  v4h qa, qb;
#pragma unroll
  for (int k = 0; k < 4; ++k) {
    qa[k] = (_Float16)(fminf(fmaxf(rintf(a[k] * scale), -128.f), 127.f) * inv);
    qb[k] = (_Float16)(fminf(fmaxf(rintf(b[k] * scale), -128.f), 127.f) * inv);
  }
  *(v4h*)d = qa;
  *(v4h*)(d + 1024) = qb;
}

// Build concatenated complex weight matrices (fp16)
__global__ __launch_bounds__(256) void wprep(
    const float* __restrict__ Wq_r, const float* __restrict__ Wq_i,
    const float* __restrict__ Wk_r, const float* __restrict__ Wk_i,
    const float* __restrict__ Wv_r, const float* __restrict__ Wv_i,
    const float* __restrict__ Wo_r, const float* __restrict__ Wo_i,
    _Float16* __restrict__ Bqkv, _Float16* __restrict__ Bo)
{
  const float* Ws[8] = {Wq_r, Wq_i, Wk_r, Wk_i, Wv_r, Wv_i, Wo_r, Wo_i};
  const int i = blockIdx.x * 256 + threadIdx.x;
  const int w = i >> 18;
  const int rem = i & 262143;
  const int j = rem >> 7;
  const int cb = (rem & 127) * 16;
  const float* src = Ws[w] + (long long)j * 2048 + cb;
  _Float16* Bp = (w < 6) ? (Bqkv + (long long)(w >> 1) * 4096 * 4096) : Bo;
  const int isI = w & 1;
  _Float16* d1 = Bp + (long long)j * 4096 + (isI ? 2048 + cb : cb);
  _Float16* d2 = Bp + (long long)(2048 + j) * 4096 + (isI ? cb : 2048 + cb);
  const float sg2 = isI ? 1.f : -1.f;
#pragma unroll
  for (int q = 0; q < 4; ++q) {
    const v4f v = *(const v4f*)(src + q * 4);
    v4h o1, o2;
#pragma unroll
    for (int k = 0; k < 4; ++k) {
      o1[k] = (_Float16)v[k];
      o2[k] = (_Float16)(v[k] * sg2);
    }
    *(v4h*)(d1 + q * 4) = o1;
    *(v4h*)(d2 + q * 4) = o2;
  }
}

// cos/sin table [T][128] float2, bf16-rounded
__global__ __launch_bounds__(256) void trig_kernel(
    const int* __restrict__ pos, float* __restrict__ cs)
{
  const int t = blockIdx.x * 2 + (threadIdx.x >> 7);
  const int d = threadIdx.x & 127;
  const float invf = (float)pow(10000.0, -(double)d / 128.0);
  const float fr = (float)pos[t] * invf;
  const double fd = (double)fr;
  cs[((long long)t * 128 + d) * 2]     = bf16_rt((float)cos(fd));
  cs[((long long)t * 128 + d) * 2 + 1] = bf16_rt((float)sin(fd));
}

// vectorized RoPE: Yq [T][8192] (qr|qi|kr|ki) -> qc/kc [NH][T][256] fp16
__global__ __launch_bounds__(256) void rope_kernel(
    const _Float16* __restrict__ Yq, const float* __restrict__ cs,
    _Float16* __restrict__ qc, _Float16* __restrict__ kc)
{
  const int idx = blockIdx.x * 256 + threadIdx.x;
  const int d0 = (idx & 15) * 8;
  const int h  = (idx >> 4) & 15;
  const int t  = idx >> 8;
  const _Float16* y = Yq + (long long)t * 8192 + h * 128 + d0;
  const v8h qr8 = *(const v8h*)(y);
  const v8h qi8 = *(const v8h*)(y + 2048);
  const v8h kr8 = *(const v8h*)(y + 4096);
  const v8h ki8 = *(const v8h*)(y + 6144);
  const float* cp = cs + ((long long)t * 128 + d0) * 2;
  v8h qro, qio, kro, kio;
#pragma unroll
  for (int u = 0; u < 8; ++u) {
    const float c = cp[u * 2], s = cp[u * 2 + 1];
    const float qr = (float)qr8[u], qi = (float)qi8[u];
    const float kr = (float)kr8[u], ki = (float)ki8[u];
    qro[u] = (_Float16)(qr * c - qi * s);
    qio[u] = (_Float16)(qi * c + qr * s);
    kro[u] = (_Float16)(kr * c - ki * s);
    kio[u] = (_Float16)(ki * c + kr * s);
  }
  _Float16* qo = qc + ((long long)h * 2048 + t) * 256 + d0;
  _Float16* ko = kc + ((long long)h * 2048 + t) * 256 + d0;
  *(v8h*)qo = qro; *(v8h*)(qo + 128) = qio;
  *(v8h*)ko = kro; *(v8h*)(ko + 128) = kio;
}

// Fused causal flash attention v2 (R2 structure, 207us verified) with
// LDS-only barriers (no vmcnt drain) + setprio on MFMA clusters.
// One block = 64 Q-rows of one head, 4 waves as 2(m)x2(n), K-tile 64,
// D=256 (r|i concat). K/V read DIRECT from global (L2-resident).
__global__ __launch_bounds__(256, 2) void flash_attn(
    const _Float16* __restrict__ qc, const _Float16* __restrict__ kc,
    const _Float16* __restrict__ vt, float* __restrict__ attn)
{
  __shared__ __align__(16) _Float16 Ps[64 * 72];   // pad 64->72 (A-frag reads)
  __shared__ float pmax[2][64];
  __shared__ float psum[2][64];

  const int h  = blockIdx.y;
  // load-balance remap: pair small-qt with large-qt across heads
  const int qt = ((h >> 3) & 1) ? (31 - (int)blockIdx.x) : (int)blockIdx.x;
  const int q0 = qt * 64;
  const int tid = threadIdx.x, lane = tid & 63, wave = tid >> 6;
  const int mi = wave >> 1, ni = wave & 1;
  const int quad = lane >> 4, l15 = lane & 15;

  const _Float16* qh = qc + (long long)h * 2048 * 256;
  const _Float16* kh = kc + (long long)h * 2048 * 256;
  const _Float16* vh = vt + (long long)h * 256 * 2048;

  // Q fragments in registers, pre-scaled by log2(e)/16 (exp2-domain softmax)
  const _Float16 scl = (_Float16)0.09016844f;
  v8h qf[2][8];
#pragma unroll
  for (int mt = 0; mt < 2; ++mt) {
    const int t = q0 + mi * 32 + mt * 16 + l15;
#pragma unroll
    for (int ks = 0; ks < 8; ++ks) {
      v8h q = *(const v8h*)(qh + (long long)t * 256 + ks * 32 + quad * 8);
#pragma unroll
      for (int u = 0; u < 8; ++u) q[u] *= scl;
      qf[mt][ks] = q;
    }
  }

  float mrow[2][4], lrow[2][4];
  v4f acc_o[2][8];
#pragma unroll
  for (int mt = 0; mt < 2; ++mt)
#pragma unroll
    for (int r = 0; r < 4; ++r) { mrow[mt][r] = -1e30f; lrow[mt][r] = 0.f; }
#pragma unroll
  for (int mt = 0; mt < 2; ++mt)
#pragma unroll
    for (int nt = 0; nt < 8; ++nt) acc_o[mt][nt] = (v4f){0.f, 0.f, 0.f, 0.f};

  for (int st = 0; st <= qt; ++st) {
    const int s0 = st * 64;

    // S quarter = Q[mi-half] @ K[ni-half]^T, K direct from global (L2-hot)
    v4f sa[2][2] = {};
#pragma unroll
    for (int ks = 0; ks < 8; ++ks) {
      v8h bk[2];
#pragma unroll
      for (int jn = 0; jn < 2; ++jn)
        bk[jn] = *(const v8h*)(kh + (long long)(s0 + ni * 32 + jn * 16 + l15) * 256
                               + ks * 32 + quad * 8);
      __builtin_amdgcn_s_setprio(1);
#pragma unroll
      for (int mt = 0; mt < 2; ++mt)
#pragma unroll
        for (int jn = 0; jn < 2; ++jn)
          sa[mt][jn] = __builtin_amdgcn_mfma_f32_16x16x32_f16(qf[mt][ks], bk[jn], sa[mt][jn], 0, 0, 0);
      __builtin_amdgcn_s_setprio(0);
    }

    const bool diag = (st == qt);
    float pm[2][4];
#pragma unroll
    for (int mt = 0; mt < 2; ++mt)
#pragma unroll
      for (int r = 0; r < 4; ++r) pm[mt][r] = -1e30f;
#pragma unroll
    for (int mt = 0; mt < 2; ++mt)
#pragma unroll
      for (int jn = 0; jn < 2; ++jn)
#pragma unroll
        for (int r = 0; r < 4; ++r) {
          float v = sa[mt][jn][r];          // already log2-scaled
          if (diag) {
            const int rl = mi * 32 + mt * 16 + quad * 4 + r;
            const int cl = ni * 32 + jn * 16 + l15;
            if (cl > rl) v = -1e30f;
          }
          sa[mt][jn][r] = v;
          pm[mt][r] = fmaxf(pm[mt][r], v);
        }
#pragma unroll
    for (int o = 1; o < 16; o <<= 1)
#pragma unroll
      for (int mt = 0; mt < 2; ++mt)
#pragma unroll
        for (int r = 0; r < 4; ++r)
          pm[mt][r] = fmaxf(pm[mt][r], __shfl_xor(pm[mt][r], o, 64));
    if (l15 == 0) {
#pragma unroll
      for (int mt = 0; mt < 2; ++mt)
#pragma unroll
        for (int r = 0; r < 4; ++r)
          pmax[ni][mi * 32 + mt * 16 + quad * 4 + r] = pm[mt][r];
    }
    LDS_BARRIER();   // B1: pmax visible (LDS drained, VMEM stays in flight)

    float al[2][4], ps[2][4];
#pragma unroll
    for (int mt = 0; mt < 2; ++mt)
#pragma unroll
      for (int r = 0; r < 4; ++r) {
        const int row = mi * 32 + mt * 16 + quad * 4 + r;
        const float mn = fmaxf(mrow[mt][r], fmaxf(pmax[0][row], pmax[1][row]));
        al[mt][r] = __builtin_amdgcn_exp2f(mrow[mt][r] - mn);
        mrow[mt][r] = mn;
        ps[mt][r] = 0.f;
      }
#pragma unroll
    for (int mt = 0; mt < 2; ++mt)
#pragma unroll
      for (int jn = 0; jn < 2; ++jn)
#pragma unroll
        for (int r = 0; r < 4; ++r) {
          const float e = __builtin_amdgcn_exp2f(sa[mt][jn][r] - mrow[mt][r]);
          ps[mt][r] += e;
          Ps[(mi * 32 + mt * 16 + quad * 4 + r) * 72 + ni * 32 + jn * 16 + l15] = (_Float16)e;
        }
#pragma unroll
    for (int o = 1; o < 16; o <<= 1)
#pragma unroll
      for (int mt = 0; mt < 2; ++mt)
#pragma unroll
        for (int r = 0; r < 4; ++r)
          ps[mt][r] += __shfl_xor(ps[mt][r], o, 64);
    if (l15 == 0) {
#pragma unroll
      for (int mt = 0; mt < 2; ++mt)
#pragma unroll
        for (int r = 0; r < 4; ++r)
          psum[ni][mi * 32 + mt * 16 + quad * 4 + r] = ps[mt][r];
    }
    LDS_BARRIER();   // B2: Ps + psum visible (VMEM stays in flight)

#pragma unroll
    for (int mt = 0; mt < 2; ++mt)
#pragma unroll
      for (int r = 0; r < 4; ++r) {
        const int row = mi * 32 + mt * 16 + quad * 4 + r;
        lrow[mt][r] = lrow[mt][r] * al[mt][r] + psum[0][row] + psum[1][row];
      }
#pragma unroll
    for (int mt = 0; mt < 2; ++mt)
#pragma unroll
      for (int nt = 0; nt < 8; ++nt)
#pragma unroll
        for (int r = 0; r < 4; ++r)
          acc_o[mt][nt][r] *= al[mt][r];

    // O += P @ V ; P from LDS, V direct from global (L2-hot)
#pragma unroll
    for (int kc2 = 0; kc2 < 2; ++kc2) {
      v8h pa[2];
#pragma unroll
      for (int mt = 0; mt < 2; ++mt) {
        const int row = mi * 32 + mt * 16 + l15;
        pa[mt] = *(const v8h*)(Ps + row * 72 + kc2 * 32 + quad * 8);
      }
#pragma unroll
      for (int nt = 0; nt < 8; ++nt) {
        const v8h vb = *(const v8h*)(vh + (long long)(ni * 128 + nt * 16 + l15) * 2048
                                     + s0 + kc2 * 32 + quad * 8);
        __builtin_amdgcn_s_setprio(1);
#pragma unroll
        for (int mt = 0; mt < 2; ++mt)
          acc_o[mt][nt] = __builtin_amdgcn_mfma_f32_16x16x32_f16(pa[mt], vb, acc_o[mt][nt], 0, 0, 0);
        __builtin_amdgcn_s_setprio(0);
      }
    }
    // no tail barrier: next-stage Ps/pmax writes are gated by B1/B2 above
  }

  // epilogue: O/l -> attn (r-part at 0, i-part at +2048*2048 floats)
#pragma unroll
  for (int mt = 0; mt < 2; ++mt) {
    float inv[4];
#pragma unroll
    for (int r = 0; r < 4; ++r) inv[r] = 1.f / lrow[mt][r];
#pragma unroll
    for (int nt = 0; nt < 8; ++nt) {
      const int d = ni * 128 + nt * 16 + l15;
      float* dst = attn + ((d < 128) ? 0ll : (2048ll * 2048)) + (h * 128 + (d & 127));
#pragma unroll
      for (int r = 0; r < 4; ++r) {
        const int t = q0 + mi * 32 + mt * 16 + quad * 4 + r;
        dst[(long long)t * 2048] = acc_o[mt][nt][r] * inv[r];
      }
    }
  }
}

extern "C" void kernel_launch(void* const* d_in, const int* in_sizes, int n_in,
                              void* d_out, int out_size, void* d_ws, size_t ws_size,
                              hipStream_t stream) {
  const float* hr   = (const float*)d_in[0];
  const float* hi   = (const float*)d_in[1];
  const int*   pos  = (const int*)d_in[2];
  const float* Wq_r = (const float*)d_in[3];
  const float* Wq_i = (const float*)d_in[4];
  const float* Wk_r = (const float*)d_in[5];
  const float* Wk_i = (const float*)d_in[6];
  const float* Wv_r = (const float*)d_in[7];
  const float* Wv_i = (const float*)d_in[8];
  const float* Wo_r = (const float*)d_in[9];
  const float* Wo_i = (const float*)d_in[10];

  char* ws = (char*)d_ws;
  _Float16* Bqkv = (_Float16*)(ws);                    // 96MB
  float*    attn = (float*)   (ws);                    // 32MB (alias, post-QKV)
  float*    cs   = (float*)   (ws + (32ll  << 20));    // 2MB  (alias, post-QKV)
  _Float16* Bo   = (_Float16*)(ws + (96ll  << 20));    // 32MB
  _Float16* Ac   = (_Float16*)(ws + (128ll << 20));    // 16MB
  _Float16* Yq   = (_Float16*)(ws + (144ll << 20));    // 32MB (q,k only)
  _Float16* qc   = (_Float16*)(ws + (176ll << 20));    // 16MB
  _Float16* kc   = (_Float16*)(ws + (192ll << 20));    // 16MB
  _Float16* vt   = (_Float16*)(ws + (208ll << 20));    // 16MB

  quant_rows<<<dim3(2048, 2), 256, 0, stream>>>(hr, hi, Ac);
  wprep<<<8192, 256, 0, stream>>>(Wq_r, Wq_i, Wk_r, Wk_i, Wv_r, Wv_i, Wo_r, Wo_i, Bqkv, Bo);
  // fused QKV: [qr|qi](2048x4096) @ Bqkv(12288x4096)^T -> Yq (q,k) + vt (v)
  gemm_qkv256<<<512, 512, 0, stream>>>(Ac, Bqkv, Yq, vt);
  trig_kernel<<<1024, 256, 0, stream>>>(pos, cs);
  rope_kernel<<<2048, 256, 0, stream>>>(Yq, cs, qc, kc);
  flash_attn<<<dim3(32, 16), 256, 0, stream>>>(qc, kc, vt, attn);
  quant_rows<<<dim3(2048, 2), 256, 0, stream>>>(attn, attn + 2048ll * 2048, Ac);
  gemm_nt<EPI_OUT><<<dim3(16, 32), 256, 0, stream>>>(
      Ac, Bo, d_out, 4096, 4096, 4096, 0, nullptr);
}

// Round 6
// 701.817 us; speedup vs baseline: 1.2616x; 1.1030x over previous
//
#include <hip/hip_runtime.h>

// ComplexNetAttention on gfx950.
// Pipeline: int8-fakequant -> fused complex QKV GEMM (fp16 MFMA, NT, K=4096;
//   8-phase counted-vmcnt schedule, 256x192 tile) -> cos/sin table +
//   vectorized RoPE -> fused flash attention v2 (R2-exact, 207us verified) ->
//   fakequant -> out GEMM (R10: 256x128 8-phase counted-vmcnt).
//
// R10 decisions from R3/R4/R5 evidence: every perturbation of R2 flash's
// sync structure regressed (occupancy 320us, barrier-free 371us, LDS-only
// barriers+setprio 251us) -> flash reverted EXACTLY to R2 (207us). The
// remaining cheap win is the out GEMM: old 128x128/BK=32 template (~731 TF)
// replaced by a parameter-reduction of the PROVEN QKV 8-phase schedule:
// 256x128 tile, BK=64, stage trios {a0,a1,b0|a2,a3,b1}, symmetric vmcnt(3),
// grid 8x32=256 = exactly 1 block/CU, XCD-chunked.

typedef float v4f __attribute__((ext_vector_type(4)));
typedef _Float16 v8h __attribute__((ext_vector_type(8)));
typedef _Float16 v4h __attribute__((ext_vector_type(4)));

typedef const __attribute__((address_space(1))) void glob_void;
typedef __attribute__((address_space(3))) void lds_void;

__device__ __forceinline__ void gload16(const _Float16* gp, _Float16* lp) {
  __builtin_amdgcn_global_load_lds((glob_void*)gp, (lds_void*)lp, 16, 0, 0);
}

// bf16 round-trip (RNE) in fp32 — matches reference's bf16 cos/sin cache.
__device__ __forceinline__ float bf16_rt(float f) {
  union { float f; unsigned u; } a; a.f = f;
  unsigned r = (a.u + 0x7fffu + ((a.u >> 16) & 1u)) & 0xffff0000u;
  union { unsigned u; float f; } b; b.u = r;
  return b.f;
}

#define SBAR()  __builtin_amdgcn_sched_barrier(0)
#define WBAR()  __builtin_amdgcn_s_barrier()
#define LGKM0() asm volatile("s_waitcnt lgkmcnt(0)" ::: "memory")

// ---------------------------------------------------------------------------
// QKV GEMM: C[2048][12288] = A[2048][4096] @ B[12288][4096]^T, fp16, fp32 acc.
// Tile 256x192, BK=64, 512 thr (8 waves 2m x 4n), wave-tile 128x48.
// 8-phase counted-vmcnt schedule (T3+T4), XOR chunk swizzle (0-conflict),
// s_setprio around MFMA clusters (T5), bijective XCD chunking (T1).
// ---------------------------------------------------------------------------
__global__ __launch_bounds__(512, 2) void gemm_qkv256(
    const _Float16* __restrict__ A, const _Float16* __restrict__ B,
    _Float16* __restrict__ Yq, _Float16* __restrict__ vt)
{
  const int p = blockIdx.x;            // 0..511, XCD = p & 7 (round-robin)
  const int xcd = p & 7, s = p >> 3;   // s: 0..63 within chunk
  const int mt = s & 7, ntl = s >> 3;
  const int nt = xcd * 8 + ntl;        // 0..63
  const int m0 = mt << 8;              // *256
  const int n0 = nt * 192;

  __shared__ __align__(16) _Float16 lds[57344];  // 2 bufs x (16384 A + 12288 B)

  const int tid = threadIdx.x, lane = tid & 63, wave = tid >> 6;
  const int quad = lane >> 4, l15 = lane & 15;
  const int wm = wave >> 2, wn = wave & 3;       // 2 x 4 waves

  // staging constants: for gload j covering LDS halfs [j*4096 + tid*8):
  // r = (j&1)*128 + tid>>2, pc = tid&3, lc = pc ^ ((r>>1)&3)
  const int rr = tid >> 2;                                   // 0..127
  const int lc8 = (((tid & 3) ^ ((tid >> 3) & 3)) << 3);     // logical chunk*8
  const _Float16* gA = A + (long long)(m0 + rr) * 4096 + lc8;
  // B tile = 24KB = 3 gloads; gload 1 crosses the ks0/ks1 subtile boundary.
  const _Float16* gBj[3];
#pragma unroll
  for (int j = 0; j < 3; ++j) {
    const int ks = (j == 2) || (j == 1 && tid >= 256);
    const int r = j * 128 + (tid >> 2) - ks * 192;
    gBj[j] = B + (long long)(n0 + r) * 4096 + ks * 32 + lc8;
  }

  // read constants: phys chunk = quad ^ ((l15>>1)&3), constant per lane
  const int co = ((quad ^ ((l15 >> 1) & 3)) << 3);
  const int aBase = (wm * 128 + l15) * 32 + co;
  const int bBase = (wn * 48 + l15) * 32 + co;

  v4f acc[8][3] = {};

  // prologue: stage tile 0 -> buf 0 in canonical order a0,a1,b0,b1,a2,a3,b2
  {
    _Float16* sd = lds + tid * 8;
    gload16(gA, sd);
    gload16(gA + 524288, sd + 4096);          // 128*4096
    gload16(gBj[0], sd + 16384);
    gload16(gBj[1], sd + 20480);
    gload16(gA + 32, sd + 8192);
    gload16(gA + 524288 + 32, sd + 12288);
    gload16(gBj[2], sd + 24576);
  }
  asm volatile("s_waitcnt vmcnt(3)" ::: "memory");  // first-4 of tile 0 done
  WBAR();

  for (int t = 0; t < 64; ++t) {
    const _Float16* As = lds + (t & 1) * 28672;
    const _Float16* Bs = As + 16384;
    _Float16* sd = lds + ((t & 1) ^ 1) * 28672 + tid * 8;
    const int k1 = (t + 1) << 6;
    const bool stg = (t < 63);

    v8h bf[3], af[4];

    // ===== P0: ds bf(ks0)+af(mh0,ks0); stage a0,a1(t+1) =====
    af[0] = *(const v8h*)&As[aBase];
    af[1] = *(const v8h*)&As[aBase + 512];
    af[2] = *(const v8h*)&As[aBase + 1024];
    af[3] = *(const v8h*)&As[aBase + 1536];
    bf[0] = *(const v8h*)&Bs[bBase];
    bf[1] = *(const v8h*)&Bs[bBase + 512];
    bf[2] = *(const v8h*)&Bs[bBase + 1024];
    if (stg) { gload16(gA + k1, sd); gload16(gA + k1 + 524288, sd + 4096); }
    SBAR(); WBAR(); LGKM0(); SBAR();
    __builtin_amdgcn_s_setprio(1);
#pragma unroll
    for (int i = 0; i < 4; ++i)
#pragma unroll
      for (int nf = 0; nf < 3; ++nf)
        acc[i][nf] = __builtin_amdgcn_mfma_f32_16x16x32_f16(af[i], bf[nf], acc[i][nf], 0, 0, 0);
    __builtin_amdgcn_s_setprio(0);
    WBAR();

    // ===== P1: ds af(mh1,ks0); stage b0,b1(t+1); vmcnt(4) =====
    af[0] = *(const v8h*)&As[aBase + 2048];
    af[1] = *(const v8h*)&As[aBase + 2560];
    af[2] = *(const v8h*)&As[aBase + 3072];
    af[3] = *(const v8h*)&As[aBase + 3584];
    if (stg) { gload16(gBj[0] + k1, sd + 16384); gload16(gBj[1] + k1, sd + 20480); }
    SBAR(); WBAR(); LGKM0(); SBAR();
    __builtin_amdgcn_s_setprio(1);
#pragma unroll
    for (int i = 0; i < 4; ++i)
#pragma unroll
      for (int nf = 0; nf < 3; ++nf)
        acc[4 + i][nf] = __builtin_amdgcn_mfma_f32_16x16x32_f16(af[i], bf[nf], acc[4 + i][nf], 0, 0, 0);
    __builtin_amdgcn_s_setprio(0);
    if (stg) asm volatile("s_waitcnt vmcnt(4)" ::: "memory");
    else     asm volatile("s_waitcnt vmcnt(0)" ::: "memory");
    WBAR();

    // ===== P2: ds bf(ks1)+af(mh0,ks1); stage a2,a3(t+1) =====
    bf[0] = *(const v8h*)&Bs[bBase + 6144];
    bf[1] = *(const v8h*)&Bs[bBase + 6656];
    bf[2] = *(const v8h*)&Bs[bBase + 7168];
    af[0] = *(const v8h*)&As[aBase + 8192];
    af[1] = *(const v8h*)&As[aBase + 8704];
    af[2] = *(const v8h*)&As[aBase + 9216];
    af[3] = *(const v8h*)&As[aBase + 9728];
    if (stg) { gload16(gA + k1 + 32, sd + 8192); gload16(gA + k1 + 524288 + 32, sd + 12288); }
    SBAR(); WBAR(); LGKM0(); SBAR();
    __builtin_amdgcn_s_setprio(1);
#pragma unroll
    for (int i = 0; i < 4; ++i)
#pragma unroll
      for (int nf = 0; nf < 3; ++nf)
        acc[i][nf] = __builtin_amdgcn_mfma_f32_16x16x32_f16(af[i], bf[nf], acc[i][nf], 0, 0, 0);
    __builtin_amdgcn_s_setprio(0);
    WBAR();

    // ===== P3: ds af(mh1,ks1); stage b2(t+1); vmcnt(3) =====
    af[0] = *(const v8h*)&As[aBase + 10240];
    af[1] = *(const v8h*)&As[aBase + 10752];
    af[2] = *(const v8h*)&As[aBase + 11264];
    af[3] = *(const v8h*)&As[aBase + 11776];
    if (stg) gload16(gBj[2] + k1, sd + 24576);
    SBAR(); WBAR(); LGKM0(); SBAR();
    __builtin_amdgcn_s_setprio(1);
#pragma unroll
    for (int i = 0; i < 4; ++i)
#pragma unroll
      for (int nf = 0; nf < 3; ++nf)
        acc[4 + i][nf] = __builtin_amdgcn_mfma_f32_16x16x32_f16(af[i], bf[nf], acc[4 + i][nf], 0, 0, 0);
    __builtin_amdgcn_s_setprio(0);
    if (stg) asm volatile("s_waitcnt vmcnt(3)" ::: "memory");
    WBAR();
  }

  // epilogue: C/D layout col=lane&15, row=quad*4+reg (m89/m91-verified)
#pragma unroll
  for (int mf = 0; mf < 8; ++mf) {
#pragma unroll
    for (int nf = 0; nf < 3; ++nf) {
      const int col = n0 + wn * 48 + nf * 16 + l15;
      const int row0 = m0 + wm * 128 + mf * 16 + quad * 4;   // multiple of 4
      if (col >= 8192) {
        // v projection -> vt[NH][256][2048], packed 4 rows per store
        const int c = col - 8192;
        const int hh = (c & 2047) >> 7;
        const int dcol = (c < 2048) ? (c & 127) : (128 + (c & 127));
        v4h pk;
#pragma unroll
        for (int r = 0; r < 4; ++r) pk[r] = (_Float16)acc[mf][nf][r];
        *(v4h*)(vt + ((long long)(hh * 256 + dcol)) * 2048 + row0) = pk;
      } else {
#pragma unroll
        for (int r = 0; r < 4; ++r)
          Yq[(long long)(row0 + r) * 8192 + col] = (_Float16)acc[mf][nf][r];
      }
    }
  }
}

// ---------------------------------------------------------------------------
// Out GEMM (R10): O[2048][4096] = A[2048][4096] @ B[4096][4096]^T, fp32 out,
// split cols [yr|yi] into concatenated halves of d_out.
// Parameter-reduction of the proven QKV 8-phase schedule: tile 256x128,
// BK=64, 512 thr (8 waves 2m x 4n), wave-tile 128x32, acc[8][2].
// LDS/buf: A [2ks][256r][32k]=16384h + B [2ks][128r][32k]=8192h = 48KB;
// double-buffered 96KB. Stage trios {a0,a1,b0 | a2,a3,b1}; symmetric
// vmcnt(3) at P1/P3 ends. Grid 8x32=256 = 1 block/CU, XCD-chunked.
// ---------------------------------------------------------------------------
__global__ __launch_bounds__(512, 2) void gemm_out256(
    const _Float16* __restrict__ A, const _Float16* __restrict__ B,
    float* __restrict__ O)
{
  const int p = blockIdx.x;            // 0..255
  const int xcd = p & 7, s = p >> 3;   // s: 0..31
  const int mt = s & 7, ntl = s >> 3;  // 8 m-tiles, 4 n-tiles per XCD
  const int nt = xcd * 4 + ntl;        // 0..31
  const int m0 = mt << 8, n0 = nt << 7;

  __shared__ __align__(16) _Float16 lds[49152];  // 2 bufs x (16384 A + 8192 B)

  const int tid = threadIdx.x, lane = tid & 63, wave = tid >> 6;
  const int quad = lane >> 4, l15 = lane & 15;
  const int wm = wave >> 2, wn = wave & 3;       // 2 x 4 waves

  const int rr = tid >> 2;                                   // 0..127
  const int lc8 = (((tid & 3) ^ ((tid >> 3) & 3)) << 3);     // logical chunk*8
  const _Float16* gA = A + (long long)(m0 + rr) * 4096 + lc8;
  const _Float16* gB = B + (long long)(n0 + rr) * 4096 + lc8;

  const int co = ((quad ^ ((l15 >> 1) & 3)) << 3);
  const int aBase = (wm * 128 + l15) * 32 + co;
  const int bBase = (wn * 32 + l15) * 32 + co;

  v4f acc[8][2] = {};

  // prologue: stage tile 0 -> buf 0, first-half trio first
  {
    _Float16* sd = lds + tid * 8;
    gload16(gA, sd);                        // a0: rows 0-127, ks0
    gload16(gA + 524288, sd + 4096);        // a1: rows 128-255, ks0
    gload16(gB, sd + 16384);                // b0: ks0
    gload16(gA + 32, sd + 8192);            // a2: rows 0-127, ks1
    gload16(gA + 524288 + 32, sd + 12288);  // a3: rows 128-255, ks1
    gload16(gB + 32, sd + 20480);           // b1: ks1
  }
  asm volatile("s_waitcnt vmcnt(3)" ::: "memory");  // first trio of tile 0
  WBAR();

  for (int t = 0; t < 64; ++t) {
    const _Float16* As = lds + (t & 1) * 24576;
    const _Float16* Bs = As + 16384;
    _Float16* sd = lds + ((t & 1) ^ 1) * 24576 + tid * 8;
    const int k1 = (t + 1) << 6;
    const bool stg = (t < 63);

    v8h bf[2], af[4];

    // ===== P0: ds af(mh0,ks0)+bf(ks0); stage a0,a1(t+1) =====
    af[0] = *(const v8h*)&As[aBase];
    af[1] = *(const v8h*)&As[aBase + 512];
    af[2] = *(const v8h*)&As[aBase + 1024];
    af[3] = *(const v8h*)&As[aBase + 1536];
    bf[0] = *(const v8h*)&Bs[bBase];
    bf[1] = *(const v8h*)&Bs[bBase + 512];
    if (stg) { gload16(gA + k1, sd); gload16(gA + k1 + 524288, sd + 4096); }
    SBAR(); WBAR(); LGKM0(); SBAR();
    __builtin_amdgcn_s_setprio(1);
#pragma unroll
    for (int i = 0; i < 4; ++i)
#pragma unroll
      for (int nf = 0; nf < 2; ++nf)
        acc[i][nf] = __builtin_amdgcn_mfma_f32_16x16x32_f16(af[i], bf[nf], acc[i][nf], 0, 0, 0);
    __builtin_amdgcn_s_setprio(0);
    WBAR();

    // ===== P1: ds af(mh1,ks0); stage b0(t+1); vmcnt(3) =====
    af[0] = *(const v8h*)&As[aBase + 2048];
    af[1] = *(const v8h*)&As[aBase + 2560];
    af[2] = *(const v8h*)&As[aBase + 3072];
    af[3] = *(const v8h*)&As[aBase + 3584];
    if (stg) gload16(gB + k1, sd + 16384);
    SBAR(); WBAR(); LGKM0(); SBAR();
    __builtin_amdgcn_s_setprio(1);
#pragma unroll
    for (int i = 0; i < 4; ++i)
#pragma unroll
      for (int nf = 0; nf < 2; ++nf)
        acc[4 + i][nf] = __builtin_amdgcn_mfma_f32_16x16x32_f16(af[i], bf[nf], acc[4 + i][nf], 0, 0, 0);
    __builtin_amdgcn_s_setprio(0);
    // retire this tile's ks1 trio {a2,a3,b1}; leave t+1's first trio in flight
    if (stg) asm volatile("s_waitcnt vmcnt(3)" ::: "memory");
    else     asm volatile("s_waitcnt vmcnt(0)" ::: "memory");
    WBAR();

    // ===== P2: ds bf(ks1)+af(mh0,ks1); stage a2,a3(t+1) =====
    bf[0] = *(const v8h*)&Bs[bBase + 4096];
    bf[1] = *(const v8h*)&Bs[bBase + 4608];
    af[0] = *(const v8h*)&As[aBase + 8192];
    af[1] = *(const v8h*)&As[aBase + 8704];
    af[2] = *(const v8h*)&As[aBase + 9216];
    af[3] = *(const v8h*)&As[aBase + 9728];
    if (stg) { gload16(gA + k1 + 32, sd + 8192); gload16(gA + k1 + 524288 + 32, sd + 12288); }
    SBAR(); WBAR(); LGKM0(); SBAR();
    __builtin_amdgcn_s_setprio(1);
#pragma unroll
    for (int i = 0; i < 4; ++i)
#pragma unroll
      for (int nf = 0; nf < 2; ++nf)
        acc[i][nf] = __builtin_amdgcn_mfma_f32_16x16x32_f16(af[i], bf[nf], acc[i][nf], 0, 0, 0);
    __builtin_amdgcn_s_setprio(0);
    WBAR();

    // ===== P3: ds af(mh1,ks1); stage b1(t+1); vmcnt(3) =====
    af[0] = *(const v8h*)&As[aBase + 10240];
    af[1] = *(const v8h*)&As[aBase + 10752];
    af[2] = *(const v8h*)&As[aBase + 11264];
    af[3] = *(const v8h*)&As[aBase + 11776];
    if (stg) gload16(gB + k1 + 32, sd + 20480);
    SBAR(); WBAR(); LGKM0(); SBAR();
    __builtin_amdgcn_s_setprio(1);
#pragma unroll
    for (int i = 0; i < 4; ++i)
#pragma unroll
      for (int nf = 0; nf < 2; ++nf)
        acc[4 + i][nf] = __builtin_amdgcn_mfma_f32_16x16x32_f16(af[i], bf[nf], acc[4 + i][nf], 0, 0, 0);
    __builtin_amdgcn_s_setprio(0);
    // retire t+1's first trio {a0,a1,b0}; leave its ks1 trio in flight
    if (stg) asm volatile("s_waitcnt vmcnt(3)" ::: "memory");
    WBAR();
  }

  // epilogue: fp32, split cols [yr|yi] into concatenated halves of d_out
#pragma unroll
  for (int mf = 0; mf < 8; ++mf) {
#pragma unroll
    for (int nf = 0; nf < 2; ++nf) {
      const int col = n0 + wn * 32 + nf * 16 + l15;
      const int row0 = m0 + wm * 128 + mf * 16 + quad * 4;
#pragma unroll
      for (int r = 0; r < 4; ++r) {
        const int row = row0 + r;
        const float v = acc[mf][nf][r];
        if (col < 2048) O[(long long)row * 2048 + col] = v;
        else O[2048ll * 2048 + (long long)row * 2048 + (col - 2048)] = v;
      }
    }
  }
}

// per-row int8 fake-quant of two [2048][2048] fp32 sources -> fp16 [2048][4096]
__global__ __launch_bounds__(256) void quant_rows(
    const float* __restrict__ s0, const float* __restrict__ s1,
    _Float16* __restrict__ dst)
{
  const int t = blockIdx.x, y = blockIdx.y;
  const float* src = (y ? s1 : s0) + (long long)t * 2048;
  const int tid = threadIdx.x, lane = tid & 63, wave = tid >> 6;
  __shared__ float rbuf[4];
  const v4f a = *(const v4f*)(src + tid * 4);
  const v4f b = *(const v4f*)(src + 1024 + tid * 4);
  float m = 0.f;
#pragma unroll
  for (int k = 0; k < 4; ++k)
    m = fmaxf(m, fmaxf(fabsf(a[k]), fabsf(b[k])));
  for (int o = 1; o < 64; o <<= 1) m = fmaxf(m, __shfl_xor(m, o, 64));
  if (lane == 0) rbuf[wave] = m;
  __syncthreads();
  m = fmaxf(fmaxf(rbuf[0], rbuf[1]), fmaxf(rbuf[2], rbuf[3]));
  const float scale = 127.f / fmaxf(m, 1e-5f);
  const float inv = 1.f / scale;
  _Float16* d = dst + (long long)t * 4096 + (long long)y * 2048 + tid * 4;
  v4h qa, qb;
#pragma unroll
  for (int k = 0; k < 4; ++k) {
    qa[k] = (_Float16)(fminf(fmaxf(rintf(a[k] * scale), -128.f), 127.f) * inv);
    qb[k] = (_Float16)(fminf(fmaxf(rintf(b[k] * scale), -128.f), 127.f) * inv);
  }
  *(v4h*)d = qa;
  *(v4h*)(d + 1024) = qb;
}

// Build concatenated complex weight matrices (fp16)
__global__ __launch_bounds__(256) void wprep(
    const float* __restrict__ Wq_r, const float* __restrict__ Wq_i,
    const float* __restrict__ Wk_r, const float* __restrict__ Wk_i,
    const float* __restrict__ Wv_r, const float* __restrict__ Wv_i,
    const float* __restrict__ Wo_r, const float* __restrict__ Wo_i,
    _Float16* __restrict__ Bqkv, _Float16* __restrict__ Bo)
{
  const float* Ws[8] = {Wq_r, Wq_i, Wk_r, Wk_i, Wv_r, Wv_i, Wo_r, Wo_i};
  const int i = blockIdx.x * 256 + threadIdx.x;
  const int w = i >> 18;
  const int rem = i & 262143;
  const int j = rem >> 7;
  const int cb = (rem & 127) * 16;
  const float* src = Ws[w] + (long long)j * 2048 + cb;
  _Float16* Bp = (w < 6) ? (Bqkv + (long long)(w >> 1) * 4096 * 4096) : Bo;
  const int isI = w & 1;
  _Float16* d1 = Bp + (long long)j * 4096 + (isI ? 2048 + cb : cb);
  _Float16* d2 = Bp + (long long)(2048 + j) * 4096 + (isI ? cb : 2048 + cb);
  const float sg2 = isI ? 1.f : -1.f;
#pragma unroll
  for (int q = 0; q < 4; ++q) {
    const v4f v = *(const v4f*)(src + q * 4);
    v4h o1, o2;
#pragma unroll
    for (int k = 0; k < 4; ++k) {
      o1[k] = (_Float16)v[k];
      o2[k] = (_Float16)(v[k] * sg2);
    }
    *(v4h*)(d1 + q * 4) = o1;
    *(v4h*)(d2 + q * 4) = o2;
  }
}

// cos/sin table [T][128] float2, bf16-rounded
__global__ __launch_bounds__(256) void trig_kernel(
    const int* __restrict__ pos, float* __restrict__ cs)
{
  const int t = blockIdx.x * 2 + (threadIdx.x >> 7);
  const int d = threadIdx.x & 127;
  const float invf = (float)pow(10000.0, -(double)d / 128.0);
  const float fr = (float)pos[t] * invf;
  const double fd = (double)fr;
  cs[((long long)t * 128 + d) * 2]     = bf16_rt((float)cos(fd));
  cs[((long long)t * 128 + d) * 2 + 1] = bf16_rt((float)sin(fd));
}

// vectorized RoPE: Yq [T][8192] (qr|qi|kr|ki) -> qc/kc [NH][T][256] fp16
__global__ __launch_bounds__(256) void rope_kernel(
    const _Float16* __restrict__ Yq, const float* __restrict__ cs,
    _Float16* __restrict__ qc, _Float16* __restrict__ kc)
{
  const int idx = blockIdx.x * 256 + threadIdx.x;
  const int d0 = (idx & 15) * 8;
  const int h  = (idx >> 4) & 15;
  const int t  = idx >> 8;
  const _Float16* y = Yq + (long long)t * 8192 + h * 128 + d0;
  const v8h qr8 = *(const v8h*)(y);
  const v8h qi8 = *(const v8h*)(y + 2048);
  const v8h kr8 = *(const v8h*)(y + 4096);
  const v8h ki8 = *(const v8h*)(y + 6144);
  const float* cp = cs + ((long long)t * 128 + d0) * 2;
  v8h qro, qio, kro, kio;
#pragma unroll
  for (int u = 0; u < 8; ++u) {
    const float c = cp[u * 2], s = cp[u * 2 + 1];
    const float qr = (float)qr8[u], qi = (float)qi8[u];
    const float kr = (float)kr8[u], ki = (float)ki8[u];
    qro[u] = (_Float16)(qr * c - qi * s);
    qio[u] = (_Float16)(qi * c + qr * s);
    kro[u] = (_Float16)(kr * c - ki * s);
    kio[u] = (_Float16)(ki * c + kr * s);
  }
  _Float16* qo = qc + ((long long)h * 2048 + t) * 256 + d0;
  _Float16* ko = kc + ((long long)h * 2048 + t) * 256 + d0;
  *(v8h*)qo = qro; *(v8h*)(qo + 128) = qio;
  *(v8h*)ko = kro; *(v8h*)(ko + 128) = kio;
}

// Fused causal flash attention v2 — EXACT R2 version (207us verified).
// One block = 64 Q-rows of one head, 4 waves as 2(m)x2(n), K-tile 64,
// D=256 (r|i concat). K/V read DIRECT from global (L2-resident), 2 barriers
// per stage. Softmax in exp2 domain; scale pre-folded into Q fragments.
__global__ __launch_bounds__(256, 2) void flash_attn(
    const _Float16* __restrict__ qc, const _Float16* __restrict__ kc,
    const _Float16* __restrict__ vt, float* __restrict__ attn)
{
  __shared__ __align__(16) _Float16 Ps[64 * 72];   // pad 64->72 (A-frag reads)
  __shared__ float pmax[2][64];
  __shared__ float psum[2][64];

  const int h  = blockIdx.y;
  // load-balance remap: pair small-qt with large-qt across heads
  const int qt = ((h >> 3) & 1) ? (31 - (int)blockIdx.x) : (int)blockIdx.x;
  const int q0 = qt * 64;
  const int tid = threadIdx.x, lane = tid & 63, wave = tid >> 6;
  const int mi = wave >> 1, ni = wave & 1;
  const int quad = lane >> 4, l15 = lane & 15;

  const _Float16* qh = qc + (long long)h * 2048 * 256;
  const _Float16* kh = kc + (long long)h * 2048 * 256;
  const _Float16* vh = vt + (long long)h * 256 * 2048;

  // Q fragments in registers, pre-scaled by log2(e)/16 (exp2-domain softmax)
  const _Float16 scl = (_Float16)0.09016844f;
  v8h qf[2][8];
#pragma unroll
  for (int mt = 0; mt < 2; ++mt) {
    const int t = q0 + mi * 32 + mt * 16 + l15;
#pragma unroll
    for (int ks = 0; ks < 8; ++ks) {
      v8h q = *(const v8h*)(qh + (long long)t * 256 + ks * 32 + quad * 8);
#pragma unroll
      for (int u = 0; u < 8; ++u) q[u] *= scl;
      qf[mt][ks] = q;
    }
  }

  float mrow[2][4], lrow[2][4];
  v4f acc_o[2][8];
#pragma unroll
  for (int mt = 0; mt < 2; ++mt)
#pragma unroll
    for (int r = 0; r < 4; ++r) { mrow[mt][r] = -1e30f; lrow[mt][r] = 0.f; }
#pragma unroll
  for (int mt = 0; mt < 2; ++mt)
#pragma unroll
    for (int nt = 0; nt < 8; ++nt) acc_o[mt][nt] = (v4f){0.f, 0.f, 0.f, 0.f};

  for (int st = 0; st <= qt; ++st) {
    const int s0 = st * 64;

    // S quarter = Q[mi-half] @ K[ni-half]^T, K direct from global (L2-hot)
    v4f sa[2][2] = {};
#pragma unroll
    for (int ks = 0; ks < 8; ++ks) {
      v8h bk[2];
#pragma unroll
      for (int jn = 0; jn < 2; ++jn)
        bk[jn] = *(const v8h*)(kh + (long long)(s0 + ni * 32 + jn * 16 + l15) * 256
                               + ks * 32 + quad * 8);
#pragma unroll
      for (int mt = 0; mt < 2; ++mt)
#pragma unroll
        for (int jn = 0; jn < 2; ++jn)
          sa[mt][jn] = __builtin_amdgcn_mfma_f32_16x16x32_f16(qf[mt][ks], bk[jn], sa[mt][jn], 0, 0, 0);
    }

    const bool diag = (st == qt);
    float pm[2][4];
#pragma unroll
    for (int mt = 0; mt < 2; ++mt)
#pragma unroll
      for (int r = 0; r < 4; ++r) pm[mt][r] = -1e30f;
#pragma unroll
    for (int mt = 0; mt < 2; ++mt)
#pragma unroll
      for (int jn = 0; jn < 2; ++jn)
#pragma unroll
        for (int r = 0; r < 4; ++r) {
          float v = sa[mt][jn][r];          // already log2-scaled
          if (diag) {
            const int rl = mi * 32 + mt * 16 + quad * 4 + r;
            const int cl = ni * 32 + jn * 16 + l15;
            if (cl > rl) v = -1e30f;
          }
          sa[mt][jn][r] = v;
          pm[mt][r] = fmaxf(pm[mt][r], v);
        }
#pragma unroll
    for (int o = 1; o < 16; o <<= 1)
#pragma unroll
      for (int mt = 0; mt < 2; ++mt)
#pragma unroll
        for (int r = 0; r < 4; ++r)
          pm[mt][r] = fmaxf(pm[mt][r], __shfl_xor(pm[mt][r], o, 64));
    if (l15 == 0) {
#pragma unroll
      for (int mt = 0; mt < 2; ++mt)
#pragma unroll
        for (int r = 0; r < 4; ++r)
          pmax[ni][mi * 32 + mt * 16 + quad * 4 + r] = pm[mt][r];
    }
    __syncthreads();   // B1: pmax visible

    float al[2][4], ps[2][4];
#pragma unroll
    for (int mt = 0; mt < 2; ++mt)
#pragma unroll
      for (int r = 0; r < 4; ++r) {
        const int row = mi * 32 + mt * 16 + quad * 4 + r;
        const float mn = fmaxf(mrow[mt][r], fmaxf(pmax[0][row], pmax[1][row]));
        al[mt][r] = __builtin_amdgcn_exp2f(mrow[mt][r] - mn);
        mrow[mt][r] = mn;
        ps[mt][r] = 0.f;
      }
#pragma unroll
    for (int mt = 0; mt < 2; ++mt)
#pragma unroll
      for (int jn = 0; jn < 2; ++jn)
#pragma unroll
        for (int r = 0; r < 4; ++r) {
          const float e = __builtin_amdgcn_exp2f(sa[mt][jn][r] - mrow[mt][r]);
          ps[mt][r] += e;
          Ps[(mi * 32 + mt * 16 + quad * 4 + r) * 72 + ni * 32 + jn * 16 + l15] = (_Float16)e;
        }
#pragma unroll
    for (int o = 1; o < 16; o <<= 1)
#pragma unroll
      for (int mt = 0; mt < 2; ++mt)
#pragma unroll
        for (int r = 0; r < 4; ++r)
          ps[mt][r] += __shfl_xor(ps[mt][r], o, 64);
    if (l15 == 0) {
#pragma unroll
      for (int mt = 0; mt < 2; ++mt)
#pragma unroll
        for (int r = 0; r < 4; ++r)
          psum[ni][mi * 32 + mt * 16 + quad * 4 + r] = ps[mt][r];
    }
    __syncthreads();   // B2: Ps + psum visible

#pragma unroll
    for (int mt = 0; mt < 2; ++mt)
#pragma unroll
      for (int r = 0; r < 4; ++r) {
        const int row = mi * 32 + mt * 16 + quad * 4 + r;
        lrow[mt][r] = lrow[mt][r] * al[mt][r] + psum[0][row] + psum[1][row];
      }
#pragma unroll
    for (int mt = 0; mt < 2; ++mt)
#pragma unroll
      for (int nt = 0; nt < 8; ++nt)
#pragma unroll
        for (int r = 0; r < 4; ++r)
          acc_o[mt][nt][r] *= al[mt][r];

    // O += P @ V ; P from LDS, V direct from global (L2-hot)
#pragma unroll
    for (int kc2 = 0; kc2 < 2; ++kc2) {
      v8h pa[2];
#pragma unroll
      for (int mt = 0; mt < 2; ++mt) {
        const int row = mi * 32 + mt * 16 + l15;
        pa[mt] = *(const v8h*)(Ps + row * 72 + kc2 * 32 + quad * 8);
      }
#pragma unroll
      for (int nt = 0; nt < 8; ++nt) {
        const v8h vb = *(const v8h*)(vh + (long long)(ni * 128 + nt * 16 + l15) * 2048
                                     + s0 + kc2 * 32 + quad * 8);
#pragma unroll
        for (int mt = 0; mt < 2; ++mt)
          acc_o[mt][nt] = __builtin_amdgcn_mfma_f32_16x16x32_f16(pa[mt], vb, acc_o[mt][nt], 0, 0, 0);
      }
    }
    // no tail barrier: next-stage Ps/pmax writes are gated by B1/B2 above
  }

  // epilogue: O/l -> attn (r-part at 0, i-part at +2048*2048 floats)
#pragma unroll
  for (int mt = 0; mt < 2; ++mt) {
    float inv[4];
#pragma unroll
    for (int r = 0; r < 4; ++r) inv[r] = 1.f / lrow[mt][r];
#pragma unroll
    for (int nt = 0; nt < 8; ++nt) {
      const int d = ni * 128 + nt * 16 + l15;
      float* dst = attn + ((d < 128) ? 0ll : (2048ll * 2048)) + (h * 128 + (d & 127));
#pragma unroll
      for (int r = 0; r < 4; ++r) {
        const int t = q0 + mi * 32 + mt * 16 + quad * 4 + r;
        dst[(long long)t * 2048] = acc_o[mt][nt][r] * inv[r];
      }
    }
  }
}

extern "C" void kernel_launch(void* const* d_in, const int* in_sizes, int n_in,
                              void* d_out, int out_size, void* d_ws, size_t ws_size,
                              hipStream_t stream) {
  const float* hr   = (const float*)d_in[0];
  const float* hi   = (const float*)d_in[1];
  const int*   pos  = (const int*)d_in[2];
  const float* Wq_r = (const float*)d_in[3];
  const float* Wq_i = (const float*)d_in[4];
  const float* Wk_r = (const float*)d_in[5];
  const float* Wk_i = (const float*)d_in[6];
  const float* Wv_r = (const float*)d_in[7];
  const float* Wv_i = (const float*)d_in[8];
  const float* Wo_r = (const float*)d_in[9];
  const float* Wo_i = (const float*)d_in[10];

  char* ws = (char*)d_ws;
  _Float16* Bqkv = (_Float16*)(ws);                    // 96MB
  float*    attn = (float*)   (ws);                    // 32MB (alias, post-QKV)
  float*    cs   = (float*)   (ws + (32ll  << 20));    // 2MB  (alias, post-QKV)
  _Float16* Bo   = (_Float16*)(ws + (96ll  << 20));    // 32MB
  _Float16* Ac   = (_Float16*)(ws + (128ll << 20));    // 16MB
  _Float16* Yq   = (_Float16*)(ws + (144ll << 20));    // 32MB (q,k only)
  _Float16* qc   = (_Float16*)(ws + (176ll << 20));    // 16MB
  _Float16* kc   = (_Float16*)(ws + (192ll << 20));    // 16MB
  _Float16* vt   = (_Float16*)(ws + (208ll << 20));    // 16MB

  quant_rows<<<dim3(2048, 2), 256, 0, stream>>>(hr, hi, Ac);
  wprep<<<8192, 256, 0, stream>>>(Wq_r, Wq_i, Wk_r, Wk_i, Wv_r, Wv_i, Wo_r, Wo_i, Bqkv, Bo);
  // fused QKV: [qr|qi](2048x4096) @ Bqkv(12288x4096)^T -> Yq (q,k) + vt (v)
  gemm_qkv256<<<512, 512, 0, stream>>>(Ac, Bqkv, Yq, vt);
  trig_kernel<<<1024, 256, 0, stream>>>(pos, cs);
  rope_kernel<<<2048, 256, 0, stream>>>(Yq, cs, qc, kc);
  flash_attn<<<dim3(32, 16), 256, 0, stream>>>(qc, kc, vt, attn);
  quant_rows<<<dim3(2048, 2), 256, 0, stream>>>(attn, attn + 2048ll * 2048, Ac);
  // output projection -> d_out = [yr (T*H) | yi (T*H)] fp32
  gemm_out256<<<256, 512, 0, stream>>>(Ac, Bo, (float*)d_out);
}

// Round 7
// 686.014 us; speedup vs baseline: 1.2906x; 1.0230x over previous
//
#include <hip/hip_runtime.h>

// ComplexNetAttention on gfx950.
// Pipeline: int8-fakequant -> fused complex QKV GEMM (fp16 MFMA, NT, K=4096;
//   8-phase counted-vmcnt schedule, 256x192 tile) -> cos/sin table +
//   vectorized RoPE -> fused flash attention v2 (R11: KBLK=128) ->
//   fakequant -> out GEMM (256x128 8-phase counted-vmcnt).
//
// R11: flash_attn keeps R2's verified sync structure EXACTLY (2 __syncthreads
// per stage, pmax/psum merge, no tail barrier) but doubles the K-tile to 128
// cols: stage count 8448 -> 4352, amortizing the per-stage fixed overhead
// (R2/R3 two-point fit: fixed ~= half the stage). R3 (smaller stages) lost,
// R4 (per-wave duplication) lost, R5 (sync edits) lost -- this is the one
// axis those results leave open. Wave-uniform live guards skip jn-tiles/PV
// slabs fully above the diagonal.

typedef float v4f __attribute__((ext_vector_type(4)));
typedef _Float16 v8h __attribute__((ext_vector_type(8)));
typedef _Float16 v4h __attribute__((ext_vector_type(4)));

typedef const __attribute__((address_space(1))) void glob_void;
typedef __attribute__((address_space(3))) void lds_void;

__device__ __forceinline__ void gload16(const _Float16* gp, _Float16* lp) {
  __builtin_amdgcn_global_load_lds((glob_void*)gp, (lds_void*)lp, 16, 0, 0);
}

// bf16 round-trip (RNE) in fp32 — matches reference's bf16 cos/sin cache.
__device__ __forceinline__ float bf16_rt(float f) {
  union { float f; unsigned u; } a; a.f = f;
  unsigned r = (a.u + 0x7fffu + ((a.u >> 16) & 1u)) & 0xffff0000u;
  union { unsigned u; float f; } b; b.u = r;
  return b.f;
}

#define SBAR()  __builtin_amdgcn_sched_barrier(0)
#define WBAR()  __builtin_amdgcn_s_barrier()
#define LGKM0() asm volatile("s_waitcnt lgkmcnt(0)" ::: "memory")

// ---------------------------------------------------------------------------
// QKV GEMM: C[2048][12288] = A[2048][4096] @ B[12288][4096]^T, fp16, fp32 acc.
// Tile 256x192, BK=64, 512 thr (8 waves 2m x 4n), wave-tile 128x48.
// 8-phase counted-vmcnt schedule (T3+T4), XOR chunk swizzle (0-conflict),
// s_setprio around MFMA clusters (T5), bijective XCD chunking (T1).
// ---------------------------------------------------------------------------
__global__ __launch_bounds__(512, 2) void gemm_qkv256(
    const _Float16* __restrict__ A, const _Float16* __restrict__ B,
    _Float16* __restrict__ Yq, _Float16* __restrict__ vt)
{
  const int p = blockIdx.x;            // 0..511, XCD = p & 7 (round-robin)
  const int xcd = p & 7, s = p >> 3;   // s: 0..63 within chunk
  const int mt = s & 7, ntl = s >> 3;
  const int nt = xcd * 8 + ntl;        // 0..63
  const int m0 = mt << 8;              // *256
  const int n0 = nt * 192;

  __shared__ __align__(16) _Float16 lds[57344];  // 2 bufs x (16384 A + 12288 B)

  const int tid = threadIdx.x, lane = tid & 63, wave = tid >> 6;
  const int quad = lane >> 4, l15 = lane & 15;
  const int wm = wave >> 2, wn = wave & 3;       // 2 x 4 waves

  // staging constants: for gload j covering LDS halfs [j*4096 + tid*8):
  // r = (j&1)*128 + tid>>2, pc = tid&3, lc = pc ^ ((r>>1)&3)
  const int rr = tid >> 2;                                   // 0..127
  const int lc8 = (((tid & 3) ^ ((tid >> 3) & 3)) << 3);     // logical chunk*8
  const _Float16* gA = A + (long long)(m0 + rr) * 4096 + lc8;
  // B tile = 24KB = 3 gloads; gload 1 crosses the ks0/ks1 subtile boundary.
  const _Float16* gBj[3];
#pragma unroll
  for (int j = 0; j < 3; ++j) {
    const int ks = (j == 2) || (j == 1 && tid >= 256);
    const int r = j * 128 + (tid >> 2) - ks * 192;
    gBj[j] = B + (long long)(n0 + r) * 4096 + ks * 32 + lc8;
  }

  // read constants: phys chunk = quad ^ ((l15>>1)&3), constant per lane
  const int co = ((quad ^ ((l15 >> 1) & 3)) << 3);
  const int aBase = (wm * 128 + l15) * 32 + co;
  const int bBase = (wn * 48 + l15) * 32 + co;

  v4f acc[8][3] = {};

  // prologue: stage tile 0 -> buf 0 in canonical order a0,a1,b0,b1,a2,a3,b2
  {
    _Float16* sd = lds + tid * 8;
    gload16(gA, sd);
    gload16(gA + 524288, sd + 4096);          // 128*4096
    gload16(gBj[0], sd + 16384);
    gload16(gBj[1], sd + 20480);
    gload16(gA + 32, sd + 8192);
    gload16(gA + 524288 + 32, sd + 12288);
    gload16(gBj[2], sd + 24576);
  }
  asm volatile("s_waitcnt vmcnt(3)" ::: "memory");  // first-4 of tile 0 done
  WBAR();

  for (int t = 0; t < 64; ++t) {
    const _Float16* As = lds + (t & 1) * 28672;
    const _Float16* Bs = As + 16384;
    _Float16* sd = lds + ((t & 1) ^ 1) * 28672 + tid * 8;
    const int k1 = (t + 1) << 6;
    const bool stg = (t < 63);

    v8h bf[3], af[4];

    // ===== P0: ds bf(ks0)+af(mh0,ks0); stage a0,a1(t+1) =====
    af[0] = *(const v8h*)&As[aBase];
    af[1] = *(const v8h*)&As[aBase + 512];
    af[2] = *(const v8h*)&As[aBase + 1024];
    af[3] = *(const v8h*)&As[aBase + 1536];
    bf[0] = *(const v8h*)&Bs[bBase];
    bf[1] = *(const v8h*)&Bs[bBase + 512];
    bf[2] = *(const v8h*)&Bs[bBase + 1024];
    if (stg) { gload16(gA + k1, sd); gload16(gA + k1 + 524288, sd + 4096); }
    SBAR(); WBAR(); LGKM0(); SBAR();
    __builtin_amdgcn_s_setprio(1);
#pragma unroll
    for (int i = 0; i < 4; ++i)
#pragma unroll
      for (int nf = 0; nf < 3; ++nf)
        acc[i][nf] = __builtin_amdgcn_mfma_f32_16x16x32_f16(af[i], bf[nf], acc[i][nf], 0, 0, 0);
    __builtin_amdgcn_s_setprio(0);
    WBAR();

    // ===== P1: ds af(mh1,ks0); stage b0,b1(t+1); vmcnt(4) =====
    af[0] = *(const v8h*)&As[aBase + 2048];
    af[1] = *(const v8h*)&As[aBase + 2560];
    af[2] = *(const v8h*)&As[aBase + 3072];
    af[3] = *(const v8h*)&As[aBase + 3584];
    if (stg) { gload16(gBj[0] + k1, sd + 16384); gload16(gBj[1] + k1, sd + 20480); }
    SBAR(); WBAR(); LGKM0(); SBAR();
    __builtin_amdgcn_s_setprio(1);
#pragma unroll
    for (int i = 0; i < 4; ++i)
#pragma unroll
      for (int nf = 0; nf < 3; ++nf)
        acc[4 + i][nf] = __builtin_amdgcn_mfma_f32_16x16x32_f16(af[i], bf[nf], acc[4 + i][nf], 0, 0, 0);
    __builtin_amdgcn_s_setprio(0);
    if (stg) asm volatile("s_waitcnt vmcnt(4)" ::: "memory");
    else     asm volatile("s_waitcnt vmcnt(0)" ::: "memory");
    WBAR();

    // ===== P2: ds bf(ks1)+af(mh0,ks1); stage a2,a3(t+1) =====
    bf[0] = *(const v8h*)&Bs[bBase + 6144];
    bf[1] = *(const v8h*)&Bs[bBase + 6656];
    bf[2] = *(const v8h*)&Bs[bBase + 7168];
    af[0] = *(const v8h*)&As[aBase + 8192];
    af[1] = *(const v8h*)&As[aBase + 8704];
    af[2] = *(const v8h*)&As[aBase + 9216];
    af[3] = *(const v8h*)&As[aBase + 9728];
    if (stg) { gload16(gA + k1 + 32, sd + 8192); gload16(gA + k1 + 524288 + 32, sd + 12288); }
    SBAR(); WBAR(); LGKM0(); SBAR();
    __builtin_amdgcn_s_setprio(1);
#pragma unroll
    for (int i = 0; i < 4; ++i)
#pragma unroll
      for (int nf = 0; nf < 3; ++nf)
        acc[i][nf] = __builtin_amdgcn_mfma_f32_16x16x32_f16(af[i], bf[nf], acc[i][nf], 0, 0, 0);
    __builtin_amdgcn_s_setprio(0);
    WBAR();

    // ===== P3: ds af(mh1,ks1); stage b2(t+1); vmcnt(3) =====
    af[0] = *(const v8h*)&As[aBase + 10240];
    af[1] = *(const v8h*)&As[aBase + 10752];
    af[2] = *(const v8h*)&As[aBase + 11264];
    af[3] = *(const v8h*)&As[aBase + 11776];
    if (stg) gload16(gBj[2] + k1, sd + 24576);
    SBAR(); WBAR(); LGKM0(); SBAR();
    __builtin_amdgcn_s_setprio(1);
#pragma unroll
    for (int i = 0; i < 4; ++i)
#pragma unroll
      for (int nf = 0; nf < 3; ++nf)
        acc[4 + i][nf] = __builtin_amdgcn_mfma_f32_16x16x32_f16(af[i], bf[nf], acc[4 + i][nf], 0, 0, 0);
    __builtin_amdgcn_s_setprio(0);
    if (stg) asm volatile("s_waitcnt vmcnt(3)" ::: "memory");
    WBAR();
  }

  // epilogue: C/D layout col=lane&15, row=quad*4+reg (m89/m91-verified)
#pragma unroll
  for (int mf = 0; mf < 8; ++mf) {
#pragma unroll
    for (int nf = 0; nf < 3; ++nf) {
      const int col = n0 + wn * 48 + nf * 16 + l15;
      const int row0 = m0 + wm * 128 + mf * 16 + quad * 4;   // multiple of 4
      if (col >= 8192) {
        // v projection -> vt[NH][256][2048], packed 4 rows per store
        const int c = col - 8192;
        const int hh = (c & 2047) >> 7;
        const int dcol = (c < 2048) ? (c & 127) : (128 + (c & 127));
        v4h pk;
#pragma unroll
        for (int r = 0; r < 4; ++r) pk[r] = (_Float16)acc[mf][nf][r];
        *(v4h*)(vt + ((long long)(hh * 256 + dcol)) * 2048 + row0) = pk;
      } else {
#pragma unroll
        for (int r = 0; r < 4; ++r)
          Yq[(long long)(row0 + r) * 8192 + col] = (_Float16)acc[mf][nf][r];
      }
    }
  }
}

// ---------------------------------------------------------------------------
// Out GEMM: O[2048][4096] = A[2048][4096] @ B[4096][4096]^T, fp32 out,
// split cols [yr|yi] into concatenated halves of d_out.
// 256x128 tile, BK=64, 8-phase counted-vmcnt (proven R10). Grid 256 = 1/CU.
// ---------------------------------------------------------------------------
__global__ __launch_bounds__(512, 2) void gemm_out256(
    const _Float16* __restrict__ A, const _Float16* __restrict__ B,
    float* __restrict__ O)
{
  const int p = blockIdx.x;            // 0..255
  const int xcd = p & 7, s = p >> 3;   // s: 0..31
  const int mt = s & 7, ntl = s >> 3;  // 8 m-tiles, 4 n-tiles per XCD
  const int nt = xcd * 4 + ntl;        // 0..31
  const int m0 = mt << 8, n0 = nt << 7;

  __shared__ __align__(16) _Float16 lds[49152];  // 2 bufs x (16384 A + 8192 B)

  const int tid = threadIdx.x, lane = tid & 63, wave = tid >> 6;
  const int quad = lane >> 4, l15 = lane & 15;
  const int wm = wave >> 2, wn = wave & 3;       // 2 x 4 waves

  const int rr = tid >> 2;                                   // 0..127
  const int lc8 = (((tid & 3) ^ ((tid >> 3) & 3)) << 3);     // logical chunk*8
  const _Float16* gA = A + (long long)(m0 + rr) * 4096 + lc8;
  const _Float16* gB = B + (long long)(n0 + rr) * 4096 + lc8;

  const int co = ((quad ^ ((l15 >> 1) & 3)) << 3);
  const int aBase = (wm * 128 + l15) * 32 + co;
  const int bBase = (wn * 32 + l15) * 32 + co;

  v4f acc[8][2] = {};

  // prologue: stage tile 0 -> buf 0, first-half trio first
  {
    _Float16* sd = lds + tid * 8;
    gload16(gA, sd);                        // a0: rows 0-127, ks0
    gload16(gA + 524288, sd + 4096);        // a1: rows 128-255, ks0
    gload16(gB, sd + 16384);                // b0: ks0
    gload16(gA + 32, sd + 8192);            // a2: rows 0-127, ks1
    gload16(gA + 524288 + 32, sd + 12288);  // a3: rows 128-255, ks1
    gload16(gB + 32, sd + 20480);           // b1: ks1
  }
  asm volatile("s_waitcnt vmcnt(3)" ::: "memory");  // first trio of tile 0
  WBAR();

  for (int t = 0; t < 64; ++t) {
    const _Float16* As = lds + (t & 1) * 24576;
    const _Float16* Bs = As + 16384;
    _Float16* sd = lds + ((t & 1) ^ 1) * 24576 + tid * 8;
    const int k1 = (t + 1) << 6;
    const bool stg = (t < 63);

    v8h bf[2], af[4];

    // ===== P0: ds af(mh0,ks0)+bf(ks0); stage a0,a1(t+1) =====
    af[0] = *(const v8h*)&As[aBase];
    af[1] = *(const v8h*)&As[aBase + 512];
    af[2] = *(const v8h*)&As[aBase + 1024];
    af[3] = *(const v8h*)&As[aBase + 1536];
    bf[0] = *(const v8h*)&Bs[bBase];
    bf[1] = *(const v8h*)&Bs[bBase + 512];
    if (stg) { gload16(gA + k1, sd); gload16(gA + k1 + 524288, sd + 4096); }
    SBAR(); WBAR(); LGKM0(); SBAR();
    __builtin_amdgcn_s_setprio(1);
#pragma unroll
    for (int i = 0; i < 4; ++i)
#pragma unroll
      for (int nf = 0; nf < 2; ++nf)
        acc[i][nf] = __builtin_amdgcn_mfma_f32_16x16x32_f16(af[i], bf[nf], acc[i][nf], 0, 0, 0);
    __builtin_amdgcn_s_setprio(0);
    WBAR();

    // ===== P1: ds af(mh1,ks0); stage b0(t+1); vmcnt(3) =====
    af[0] = *(const v8h*)&As[aBase + 2048];
    af[1] = *(const v8h*)&As[aBase + 2560];
    af[2] = *(const v8h*)&As[aBase + 3072];
    af[3] = *(const v8h*)&As[aBase + 3584];
    if (stg) gload16(gB + k1, sd + 16384);
    SBAR(); WBAR(); LGKM0(); SBAR();
    __builtin_amdgcn_s_setprio(1);
#pragma unroll
    for (int i = 0; i < 4; ++i)
#pragma unroll
      for (int nf = 0; nf < 2; ++nf)
        acc[4 + i][nf] = __builtin_amdgcn_mfma_f32_16x16x32_f16(af[i], bf[nf], acc[4 + i][nf], 0, 0, 0);
    __builtin_amdgcn_s_setprio(0);
    // retire this tile's ks1 trio {a2,a3,b1}; leave t+1's first trio in flight
    if (stg) asm volatile("s_waitcnt vmcnt(3)" ::: "memory");
    else     asm volatile("s_waitcnt vmcnt(0)" ::: "memory");
    WBAR();

    // ===== P2: ds bf(ks1)+af(mh0,ks1); stage a2,a3(t+1) =====
    bf[0] = *(const v8h*)&Bs[bBase + 4096];
    bf[1] = *(const v8h*)&Bs[bBase + 4608];
    af[0] = *(const v8h*)&As[aBase + 8192];
    af[1] = *(const v8h*)&As[aBase + 8704];
    af[2] = *(const v8h*)&As[aBase + 9216];
    af[3] = *(const v8h*)&As[aBase + 9728];
    if (stg) { gload16(gA + k1 + 32, sd + 8192); gload16(gA + k1 + 524288 + 32, sd + 12288); }
    SBAR(); WBAR(); LGKM0(); SBAR();
    __builtin_amdgcn_s_setprio(1);
#pragma unroll
    for (int i = 0; i < 4; ++i)
#pragma unroll
      for (int nf = 0; nf < 2; ++nf)
        acc[i][nf] = __builtin_amdgcn_mfma_f32_16x16x32_f16(af[i], bf[nf], acc[i][nf], 0, 0, 0);
    __builtin_amdgcn_s_setprio(0);
    WBAR();

    // ===== P3: ds af(mh1,ks1); stage b1(t+1); vmcnt(3) =====
    af[0] = *(const v8h*)&As[aBase + 10240];
    af[1] = *(const v8h*)&As[aBase + 10752];
    af[2] = *(const v8h*)&As[aBase + 11264];
    af[3] = *(const v8h*)&As[aBase + 11776];
    if (stg) gload16(gB + k1 + 32, sd + 20480);
    SBAR(); WBAR(); LGKM0(); SBAR();
    __builtin_amdgcn_s_setprio(1);
#pragma unroll
    for (int i = 0; i < 4; ++i)
#pragma unroll
      for (int nf = 0; nf < 2; ++nf)
        acc[4 + i][nf] = __builtin_amdgcn_mfma_f32_16x16x32_f16(af[i], bf[nf], acc[4 + i][nf], 0, 0, 0);
    __builtin_amdgcn_s_setprio(0);
    // retire t+1's first trio {a0,a1,b0}; leave its ks1 trio in flight
    if (stg) asm volatile("s_waitcnt vmcnt(3)" ::: "memory");
    WBAR();
  }

  // epilogue: fp32, split cols [yr|yi] into concatenated halves of d_out
#pragma unroll
  for (int mf = 0; mf < 8; ++mf) {
#pragma unroll
    for (int nf = 0; nf < 2; ++nf) {
      const int col = n0 + wn * 32 + nf * 16 + l15;
      const int row0 = m0 + wm * 128 + mf * 16 + quad * 4;
#pragma unroll
      for (int r = 0; r < 4; ++r) {
        const int row = row0 + r;
        const float v = acc[mf][nf][r];
        if (col < 2048) O[(long long)row * 2048 + col] = v;
        else O[2048ll * 2048 + (long long)row * 2048 + (col - 2048)] = v;
      }
    }
  }
}

// per-row int8 fake-quant of two [2048][2048] fp32 sources -> fp16 [2048][4096]
__global__ __launch_bounds__(256) void quant_rows(
    const float* __restrict__ s0, const float* __restrict__ s1,
    _Float16* __restrict__ dst)
{
  const int t = blockIdx.x, y = blockIdx.y;
  const float* src = (y ? s1 : s0) + (long long)t * 2048;
  const int tid = threadIdx.x, lane = tid & 63, wave = tid >> 6;
  __shared__ float rbuf[4];
  const v4f a = *(const v4f*)(src + tid * 4);
  const v4f b = *(const v4f*)(src + 1024 + tid * 4);
  float m = 0.f;
#pragma unroll
  for (int k = 0; k < 4; ++k)
    m = fmaxf(m, fmaxf(fabsf(a[k]), fabsf(b[k])));
  for (int o = 1; o < 64; o <<= 1) m = fmaxf(m, __shfl_xor(m, o, 64));
  if (lane == 0) rbuf[wave] = m;
  __syncthreads();
  m = fmaxf(fmaxf(rbuf[0], rbuf[1]), fmaxf(rbuf[2], rbuf[3]));
  const float scale = 127.f / fmaxf(m, 1e-5f);
  const float inv = 1.f / scale;
  _Float16* d = dst + (long long)t * 4096 + (long long)y * 2048 + tid * 4;
  v4h qa, qb;
#pragma unroll
  for (int k = 0; k < 4; ++k) {
    qa[k] = (_Float16)(fminf(fmaxf(rintf(a[k] * scale), -128.f), 127.f) * inv);
    qb[k] = (_Float16)(fminf(fmaxf(rintf(b[k] * scale), -128.f), 127.f) * inv);
  }
  *(v4h*)d = qa;
  *(v4h*)(d + 1024) = qb;
}

// Build concatenated complex weight matrices (fp16)
__global__ __launch_bounds__(256) void wprep(
    const float* __restrict__ Wq_r, const float* __restrict__ Wq_i,
    const float* __restrict__ Wk_r, const float* __restrict__ Wk_i,
    const float* __restrict__ Wv_r, const float* __restrict__ Wv_i,
    const float* __restrict__ Wo_r, const float* __restrict__ Wo_i,
    _Float16* __restrict__ Bqkv, _Float16* __restrict__ Bo)
{
  const float* Ws[8] = {Wq_r, Wq_i, Wk_r, Wk_i, Wv_r, Wv_i, Wo_r, Wo_i};
  const int i = blockIdx.x * 256 + threadIdx.x;
  const int w = i >> 18;
  const int rem = i & 262143;
  const int j = rem >> 7;
  const int cb = (rem & 127) * 16;
  const float* src = Ws[w] + (long long)j * 2048 + cb;
  _Float16* Bp = (w < 6) ? (Bqkv + (long long)(w >> 1) * 4096 * 4096) : Bo;
  const int isI = w & 1;
  _Float16* d1 = Bp + (long long)j * 4096 + (isI ? 2048 + cb : cb);
  _Float16* d2 = Bp + (long long)(2048 + j) * 4096 + (isI ? cb : 2048 + cb);
  const float sg2 = isI ? 1.f : -1.f;
#pragma unroll
  for (int q = 0; q < 4; ++q) {
    const v4f v = *(const v4f*)(src + q * 4);
    v4h o1, o2;
#pragma unroll
    for (int k = 0; k < 4; ++k) {
      o1[k] = (_Float16)v[k];
      o2[k] = (_Float16)(v[k] * sg2);
    }
    *(v4h*)(d1 + q * 4) = o1;
    *(v4h*)(d2 + q * 4) = o2;
  }
}

// cos/sin table [T][128] float2, bf16-rounded
__global__ __launch_bounds__(256) void trig_kernel(
    const int* __restrict__ pos, float* __restrict__ cs)
{
  const int t = blockIdx.x * 2 + (threadIdx.x >> 7);
  const int d = threadIdx.x & 127;
  const float invf = (float)pow(10000.0, -(double)d / 128.0);
  const float fr = (float)pos[t] * invf;
  const double fd = (double)fr;
  cs[((long long)t * 128 + d) * 2]     = bf16_rt((float)cos(fd));
  cs[((long long)t * 128 + d) * 2 + 1] = bf16_rt((float)sin(fd));
}

// vectorized RoPE: Yq [T][8192] (qr|qi|kr|ki) -> qc/kc [NH][T][256] fp16
__global__ __launch_bounds__(256) void rope_kernel(
    const _Float16* __restrict__ Yq, const float* __restrict__ cs,
    _Float16* __restrict__ qc, _Float16* __restrict__ kc)
{
  const int idx = blockIdx.x * 256 + threadIdx.x;
  const int d0 = (idx & 15) * 8;
  const int h  = (idx >> 4) & 15;
  const int t  = idx >> 8;
  const _Float16* y = Yq + (long long)t * 8192 + h * 128 + d0;
  const v8h qr8 = *(const v8h*)(y);
  const v8h qi8 = *(const v8h*)(y + 2048);
  const v8h kr8 = *(const v8h*)(y + 4096);
  const v8h ki8 = *(const v8h*)(y + 6144);
  const float* cp = cs + ((long long)t * 128 + d0) * 2;
  v8h qro, qio, kro, kio;
#pragma unroll
  for (int u = 0; u < 8; ++u) {
    const float c = cp[u * 2], s = cp[u * 2 + 1];
    const float qr = (float)qr8[u], qi = (float)qi8[u];
    const float kr = (float)kr8[u], ki = (float)ki8[u];
    qro[u] = (_Float16)(qr * c - qi * s);
    qio[u] = (_Float16)(qi * c + qr * s);
    kro[u] = (_Float16)(kr * c - ki * s);
    kio[u] = (_Float16)(ki * c + kr * s);
  }
  _Float16* qo = qc + ((long long)h * 2048 + t) * 256 + d0;
  _Float16* ko = kc + ((long long)h * 2048 + t) * 256 + d0;
  *(v8h*)qo = qro; *(v8h*)(qo + 128) = qio;
  *(v8h*)ko = kro; *(v8h*)(ko + 128) = kio;
}

// Fused causal flash attention v2 — R2 sync structure, KBLK=128 (R11).
// One block = 64 Q-rows of one head, 4 waves as 2(m)x2(n: 64-col halves),
// K-tile 128, D=256 (r|i concat). K/V direct from global (L2-resident),
// 2 __syncthreads per stage (unchanged from R2). Stage count halved.
__global__ __launch_bounds__(256, 2) void flash_attn(
    const _Float16* __restrict__ qc, const _Float16* __restrict__ kc,
    const _Float16* __restrict__ vt, float* __restrict__ attn)
{
  __shared__ __align__(16) _Float16 Ps[64 * 136];  // 128 cols, pad ->136
  __shared__ float pmax[2][64];
  __shared__ float psum[2][64];

  const int h  = blockIdx.y;
  // load-balance remap: pair small-qt with large-qt across heads
  const int qt = ((h >> 3) & 1) ? (31 - (int)blockIdx.x) : (int)blockIdx.x;
  const int q0 = qt * 64;
  const int tid = threadIdx.x, lane = tid & 63, wave = tid >> 6;
  const int mi = wave >> 1, ni = wave & 1;
  const int quad = lane >> 4, l15 = lane & 15;

  const _Float16* qh = qc + (long long)h * 2048 * 256;
  const _Float16* kh = kc + (long long)h * 2048 * 256;
  const _Float16* vh = vt + (long long)h * 256 * 2048;

  // Q fragments in registers, pre-scaled by log2(e)/16 (exp2-domain softmax)
  const _Float16 scl = (_Float16)0.09016844f;
  v8h qf[2][8];
#pragma unroll
  for (int mt = 0; mt < 2; ++mt) {
    const int t = q0 + mi * 32 + mt * 16 + l15;
#pragma unroll
    for (int ks = 0; ks < 8; ++ks) {
      v8h q = *(const v8h*)(qh + (long long)t * 256 + ks * 32 + quad * 8);
#pragma unroll
      for (int u = 0; u < 8; ++u) q[u] *= scl;
      qf[mt][ks] = q;
    }
  }

  float mrow[2][4], lrow[2][4];
  v4f acc_o[2][8];
#pragma unroll
  for (int mt = 0; mt < 2; ++mt)
#pragma unroll
    for (int r = 0; r < 4; ++r) { mrow[mt][r] = -1e30f; lrow[mt][r] = 0.f; }
#pragma unroll
  for (int mt = 0; mt < 2; ++mt)
#pragma unroll
    for (int nt = 0; nt < 8; ++nt) acc_o[mt][nt] = (v4f){0.f, 0.f, 0.f, 0.f};

  const int nst = (qt >> 1) + 1;
  for (int st = 0; st < nst; ++st) {
    const int s0 = st * 128;
    const bool diag = (st == nst - 1);

    // wave-uniform liveness of each 16-col jn tile (cols fully above diag?)
    bool live[4];
#pragma unroll
    for (int jn = 0; jn < 4; ++jn)
      live[jn] = !diag || (s0 + ni * 64 + jn * 16 <= q0 + 63);

    // S half = Q @ K[128 cols; this wave's 64-col half]^T, K direct from L2
    v4f sa[2][4] = {};
#pragma unroll
    for (int ks = 0; ks < 8; ++ks) {
      v8h bk[4];
#pragma unroll
      for (int jn = 0; jn < 4; ++jn)
        if (live[jn])
          bk[jn] = *(const v8h*)(kh + (long long)(s0 + ni * 64 + jn * 16 + l15) * 256
                                 + ks * 32 + quad * 8);
#pragma unroll
      for (int mt = 0; mt < 2; ++mt)
#pragma unroll
        for (int jn = 0; jn < 4; ++jn)
          if (live[jn])
            sa[mt][jn] = __builtin_amdgcn_mfma_f32_16x16x32_f16(qf[mt][ks], bk[jn], sa[mt][jn], 0, 0, 0);
    }

    float pm[2][4];
#pragma unroll
    for (int mt = 0; mt < 2; ++mt)
#pragma unroll
      for (int r = 0; r < 4; ++r) pm[mt][r] = -1e30f;
#pragma unroll
    for (int mt = 0; mt < 2; ++mt)
#pragma unroll
      for (int jn = 0; jn < 4; ++jn)
#pragma unroll
        for (int r = 0; r < 4; ++r) {
          float v = sa[mt][jn][r];          // already log2-scaled
          if (diag) {
            const int rl = q0 + mi * 32 + mt * 16 + quad * 4 + r;
            const int cl = s0 + ni * 64 + jn * 16 + l15;
            if (cl > rl) v = -1e30f;
          }
          sa[mt][jn][r] = v;
          pm[mt][r] = fmaxf(pm[mt][r], v);
        }
#pragma unroll
    for (int o = 1; o < 16; o <<= 1)
#pragma unroll
      for (int mt = 0; mt < 2; ++mt)
#pragma unroll
        for (int r = 0; r < 4; ++r)
          pm[mt][r] = fmaxf(pm[mt][r], __shfl_xor(pm[mt][r], o, 64));
    if (l15 == 0) {
#pragma unroll
      for (int mt = 0; mt < 2; ++mt)
#pragma unroll
        for (int r = 0; r < 4; ++r)
          pmax[ni][mi * 32 + mt * 16 + quad * 4 + r] = pm[mt][r];
    }
    __syncthreads();   // B1: pmax visible

    float al[2][4], ps[2][4];
#pragma unroll
    for (int mt = 0; mt < 2; ++mt)
#pragma unroll
      for (int r = 0; r < 4; ++r) {
        const int row = mi * 32 + mt * 16 + quad * 4 + r;
        const float mn = fmaxf(mrow[mt][r], fmaxf(pmax[0][row], pmax[1][row]));
        al[mt][r] = __builtin_amdgcn_exp2f(mrow[mt][r] - mn);
        mrow[mt][r] = mn;
        ps[mt][r] = 0.f;
      }
#pragma unroll
    for (int mt = 0; mt < 2; ++mt)
#pragma unroll
      for (int jn = 0; jn < 4; ++jn)
#pragma unroll
        for (int r = 0; r < 4; ++r) {
          const float e = __builtin_amdgcn_exp2f(sa[mt][jn][r] - mrow[mt][r]);
          ps[mt][r] += e;
          Ps[(mi * 32 + mt * 16 + quad * 4 + r) * 136 + ni * 64 + jn * 16 + l15] = (_Float16)e;
        }
#pragma unroll
    for (int o = 1; o < 16; o <<= 1)
#pragma unroll
      for (int mt = 0; mt < 2; ++mt)
#pragma unroll
        for (int r = 0; r < 4; ++r)
          ps[mt][r] += __shfl_xor(ps[mt][r], o, 64);
    if (l15 == 0) {
#pragma unroll
      for (int mt = 0; mt < 2; ++mt)
#pragma unroll
        for (int r = 0; r < 4; ++r)
          psum[ni][mi * 32 + mt * 16 + quad * 4 + r] = ps[mt][r];
    }
    __syncthreads();   // B2: Ps + psum visible

#pragma unroll
    for (int mt = 0; mt < 2; ++mt)
#pragma unroll
      for (int r = 0; r < 4; ++r) {
        const int row = mi * 32 + mt * 16 + quad * 4 + r;
        lrow[mt][r] = lrow[mt][r] * al[mt][r] + psum[0][row] + psum[1][row];
      }
#pragma unroll
    for (int mt = 0; mt < 2; ++mt)
#pragma unroll
      for (int nt = 0; nt < 8; ++nt)
#pragma unroll
        for (int r = 0; r < 4; ++r)
          acc_o[mt][nt][r] *= al[mt][r];

    // O += P @ V over 128 cols; P from LDS, V direct from global (L2-hot).
    // Slabs fully above the diagonal carry P==0 -> skip (wave-uniform).
#pragma unroll
    for (int kc2 = 0; kc2 < 4; ++kc2) {
      if (diag && (s0 + kc2 * 32 > q0 + 63)) continue;
      v8h pa[2];
#pragma unroll
      for (int mt = 0; mt < 2; ++mt) {
        const int row = mi * 32 + mt * 16 + l15;
        pa[mt] = *(const v8h*)(Ps + row * 136 + kc2 * 32 + quad * 8);
      }
#pragma unroll
      for (int nt = 0; nt < 8; ++nt) {
        const v8h vb = *(const v8h*)(vh + (long long)(ni * 128 + nt * 16 + l15) * 2048
                                     + s0 + kc2 * 32 + quad * 8);
#pragma unroll
        for (int mt = 0; mt < 2; ++mt)
          acc_o[mt][nt] = __builtin_amdgcn_mfma_f32_16x16x32_f16(pa[mt], vb, acc_o[mt][nt], 0, 0, 0);
      }
    }
    // no tail barrier: next-stage Ps/pmax writes are gated by B1/B2 above
  }

  // epilogue: O/l -> attn (r-part at 0, i-part at +2048*2048 floats)
#pragma unroll
  for (int mt = 0; mt < 2; ++mt) {
    float inv[4];
#pragma unroll
    for (int r = 0; r < 4; ++r) inv[r] = 1.f / lrow[mt][r];
#pragma unroll
    for (int nt = 0; nt < 8; ++nt) {
      const int d = ni * 128 + nt * 16 + l15;
      float* dst = attn + ((d < 128) ? 0ll : (2048ll * 2048)) + (h * 128 + (d & 127));
#pragma unroll
      for (int r = 0; r < 4; ++r) {
        const int t = q0 + mi * 32 + mt * 16 + quad * 4 + r;
        dst[(long long)t * 2048] = acc_o[mt][nt][r] * inv[r];
      }
    }
  }
}

extern "C" void kernel_launch(void* const* d_in, const int* in_sizes, int n_in,
                              void* d_out, int out_size, void* d_ws, size_t ws_size,
                              hipStream_t stream) {
  const float* hr   = (const float*)d_in[0];
  const float* hi   = (const float*)d_in[1];
  const int*   pos  = (const int*)d_in[2];
  const float* Wq_r = (const float*)d_in[3];
  const float* Wq_i = (const float*)d_in[4];
  const float* Wk_r = (const float*)d_in[5];
  const float* Wk_i = (const float*)d_in[6];
  const float* Wv_r = (const float*)d_in[7];
  const float* Wv_i = (const float*)d_in[8];
  const float* Wo_r = (const float*)d_in[9];
  const float* Wo_i = (const float*)d_in[10];

  char* ws = (char*)d_ws;
  _Float16* Bqkv = (_Float16*)(ws);                    // 96MB
  float*    attn = (float*)   (ws);                    // 32MB (alias, post-QKV)
  float*    cs   = (float*)   (ws + (32ll  << 20));    // 2MB  (alias, post-QKV)
  _Float16* Bo   = (_Float16*)(ws + (96ll  << 20));    // 32MB
  _Float16* Ac   = (_Float16*)(ws + (128ll << 20));    // 16MB
  _Float16* Yq   = (_Float16*)(ws + (144ll << 20));    // 32MB (q,k only)
  _Float16* qc   = (_Float16*)(ws + (176ll << 20));    // 16MB
  _Float16* kc   = (_Float16*)(ws + (192ll << 20));    // 16MB
  _Float16* vt   = (_Float16*)(ws + (208ll << 20));    // 16MB

  quant_rows<<<dim3(2048, 2), 256, 0, stream>>>(hr, hi, Ac);
  wprep<<<8192, 256, 0, stream>>>(Wq_r, Wq_i, Wk_r, Wk_i, Wv_r, Wv_i, Wo_r, Wo_i, Bqkv, Bo);
  // fused QKV: [qr|qi](2048x4096) @ Bqkv(12288x4096)^T -> Yq (q,k) + vt (v)
  gemm_qkv256<<<512, 512, 0, stream>>>(Ac, Bqkv, Yq, vt);
  trig_kernel<<<1024, 256, 0, stream>>>(pos, cs);
  rope_kernel<<<2048, 256, 0, stream>>>(Yq, cs, qc, kc);
  flash_attn<<<dim3(32, 16), 256, 0, stream>>>(qc, kc, vt, attn);
  quant_rows<<<dim3(2048, 2), 256, 0, stream>>>(attn, attn + 2048ll * 2048, Ac);
  // output projection -> d_out = [yr (T*H) | yi (T*H)] fp32
  gemm_out256<<<256, 512, 0, stream>>>(Ac, Bo, (float*)d_out);
}